// Round 12
// baseline (224.933 us; speedup 1.0000x reference)
//
#include <hip/hip_runtime.h>
#include <hip/hip_bf16.h>

#define BATCH 8
#define NPTS 2048
#define LATENT 128

typedef __attribute__((ext_vector_type(8))) short short8;
typedef __attribute__((ext_vector_type(4))) float f32x4;

__device__ __forceinline__ ushort f2bf(float f) {
  unsigned int b = __float_as_uint(f);
  b += 0x7FFF + ((b >> 16) & 1);
  return (ushort)(b >> 16);
}
__device__ __forceinline__ float bf2f(ushort u) {
  return __uint_as_float(((unsigned int)u) << 16);
}
// packed bf16 convert (v_cvt_pk_bf16_f32 on gfx950), RNE — same as f2bf
__device__ __forceinline__ unsigned int pkbf(float a, float b) {
  __hip_bfloat162 h = __float22bfloat162_rn(make_float2(a, b));
  return *(unsigned int*)&h;
}

// log2(e) and sqrt(2*log2(e)) — points are stored in exp2-space
#define L2E 1.4426950408889634f
#define SC2 1.6986436f

// ---------------------------------------------------------------------------
// setup: bid 0..7 = prep (centroid + pnt), 8..9 = WT1, 10..17 = WT2,
//        18..25 = WzT. WT[n][k] = bf16(W[k][n]).
// pnt[b][n] = (SC2*xc, -|xc|^2*L2E): pi.w+pj.w+dot(pi.xyz,pj.xyz) = -L2E*dist.
// ---------------------------------------------------------------------------
__device__ __forceinline__ void wtrans_tile(const float* __restrict__ W,
    ushort* __restrict__ WT, int K, int N, int n0, int k0, int tid) {
  __shared__ ushort s[64][72];
  for (int i = tid; i < 64 * 64; i += 256) {
    const int kl = i >> 6, nl = i & 63;
    s[kl][nl] = f2bf(W[(size_t)(k0 + kl) * N + n0 + nl]);
  }
  __syncthreads();
  for (int i = tid; i < 64 * 64; i += 256) {
    const int nl = i >> 6, kl = i & 63;
    WT[(size_t)(n0 + nl) * K + k0 + kl] = s[kl][nl];
  }
}

__global__ __launch_bounds__(256) void setup_kernel(const float* __restrict__ x,
    const float* __restrict__ mask, float4* __restrict__ pnt,
    const float* __restrict__ W1, ushort* __restrict__ WT1,
    const float* __restrict__ W2, ushort* __restrict__ WT2,
    const float* __restrict__ Wz, ushort* __restrict__ WzT) {
  const int bid = blockIdx.x;
  const int tid = threadIdx.x;
  if (bid >= 8) {
    if (bid < 10) wtrans_tile(W1, WT1, 64, 128, (bid - 8) * 64, 0, tid);
    else if (bid < 18) {
      const int idx = bid - 10;
      wtrans_tile(W2, WT2, 128, 256, (idx & 3) * 64, (idx >> 2) * 64, tid);
    } else {
      const int idx = bid - 18;
      wtrans_tile(Wz, WzT, 256, 128, (idx & 1) * 64, (idx >> 1) * 64, tid);
    }
    return;
  }
  const int b = bid;
  const float* xb = x + (size_t)b * NPTS * 3;
  const float* mb = mask + (size_t)b * NPTS;
  float s0 = 0.f, s1 = 0.f, s2 = 0.f, c = 0.f;
  for (int n = tid; n < NPTS; n += 256) {
    float m = mb[n];
    s0 += xb[n * 3 + 0] * m;
    s1 += xb[n * 3 + 1] * m;
    s2 += xb[n * 3 + 2] * m;
    c += m;
  }
  __shared__ float red[4][256];
  red[0][tid] = s0; red[1][tid] = s1; red[2][tid] = s2; red[3][tid] = c;
  __syncthreads();
  for (int off = 128; off > 0; off >>= 1) {
    if (tid < off) {
      red[0][tid] += red[0][tid + off];
      red[1][tid] += red[1][tid + off];
      red[2][tid] += red[2][tid + off];
      red[3][tid] += red[3][tid + off];
    }
    __syncthreads();
  }
  const float cnt = fmaxf(red[3][0], 1.0f);
  const float c0 = red[0][0] / cnt, c1 = red[1][0] / cnt, c2 = red[2][0] / cnt;
  float4* pb = pnt + (size_t)b * NPTS;
  for (int n = tid; n < NPTS; n += 256) {
    const float a0 = xb[n * 3 + 0] - c0;
    const float a1 = xb[n * 3 + 1] - c1;
    const float a2 = xb[n * 3 + 2] - c2;
    pb[n] = make_float4(a0 * SC2, a1 * SC2, a2 * SC2,
                        -(a0 * a0 + a1 * a1 + a2 * a2) * L2E);
  }
}

// ---------------------------------------------------------------------------
// layer 0 fused: aggregation (D=3, VALU, 8-way j-split) + dense 3->64 +
// LN + swish + transposed bf16 write h1T[b][d][n]. 64 rows/block, 512 thr.
// ---------------------------------------------------------------------------
__global__ __launch_bounds__(512) void layer0_kernel(
    const float4* __restrict__ pnt, const float* __restrict__ W,
    const float* __restrict__ bias, const float* __restrict__ g,
    const float* __restrict__ be, ushort* __restrict__ hout) {
  const int b = blockIdx.y;
  const int i0 = blockIdx.x * 64;
  const int tid = threadIdx.x;
  const int il = tid & 63, part = tid >> 6;   // 8 j-parts
  const float4* pb = pnt + (size_t)b * NPTS;
  const float4 pi = pb[i0 + il];
  float a0 = 0.f, a1 = 0.f, a2 = 0.f, dn = 0.f;
#pragma unroll 8
  for (int j = part * 256; j < part * 256 + 256; j++) {
    const float4 pj = pb[j];
    float arg = pi.w + pj.w;
    arg = fmaf(pi.x, pj.x, arg);
    arg = fmaf(pi.y, pj.y, arg);
    arg = fmaf(pi.z, pj.z, arg);
    const float w = __builtin_amdgcn_exp2f(arg);
    a0 = fmaf(w, pj.x, a0);
    a1 = fmaf(w, pj.y, a1);
    a2 = fmaf(w, pj.z, a2);
    dn += w;
  }
  __shared__ float4 sred[8][64];
  __shared__ float srow[64 * 3];
  __shared__ ushort lt[64][64];
  sred[part][il] = make_float4(a0, a1, a2, dn);
  __syncthreads();
  if (tid < 64) {
    float A0 = 0.f, A1 = 0.f, A2 = 0.f, DN = 0.f;
#pragma unroll
    for (int p = 0; p < 8; p++) {
      const float4 r = sred[p][tid];
      A0 += r.x; A1 += r.y; A2 += r.z; DN += r.w;
    }
    const float inv = 1.0f / (DN * SC2);   // undo SC2 scaling of xyz
    srow[tid * 3 + 0] = A0 * inv;
    srow[tid * 3 + 1] = A1 * inv;
    srow[tid * 3 + 2] = A2 * inv;
  }
  __syncthreads();
  const int wv = tid >> 6, lane = tid & 63;
  const float w0c = W[lane], w1c = W[64 + lane], w2c = W[128 + lane];
  const float gv = g[lane], bev = be[lane], bv = bias[lane];
#pragma unroll
  for (int r = 0; r < 8; r++) {
    const int row = wv * 8 + r;
    float o = bv;
    o = fmaf(srow[row * 3 + 0], w0c, o);
    o = fmaf(srow[row * 3 + 1], w1c, o);
    o = fmaf(srow[row * 3 + 2], w2c, o);
    float m1 = o, m2 = o * o;
#pragma unroll
    for (int off = 32; off > 0; off >>= 1) {
      m1 += __shfl_xor(m1, off, 64);
      m2 += __shfl_xor(m2, off, 64);
    }
    const float mu = m1 / 64.f;
    const float rstd = rsqrtf(m2 / 64.f - mu * mu + 1e-6f);
    const float v = (o - mu) * rstd * gv + bev;
    const float act = v / (1.0f + __expf(-v));
    lt[row][lane] = f2bf(act);
  }
  __syncthreads();
  if (tid < 64) {
    ushort tmp[64];
#pragma unroll
    for (int r = 0; r < 64; r++) tmp[r] = lt[r][tid];
    ushort* dst = hout + ((size_t)b * 64 + tid) * NPTS + i0;
#pragma unroll
    for (int c = 0; c < 8; c++)
      *(uint4*)(dst + c * 8) = *(uint4*)&tmp[c * 8];
  }
}

// ---------------------------------------------------------------------------
// FUSED layer v9 — barrier-free K-loop, 16 rows/block, 1024 blocks:
//  - 256 threads, 4 waves = j-quarters; each wave one A-frag (16 rows).
//    Grid = 1024 -> 4 blocks/CU x 4 waves = 16 waves/CU (2x R10 TLP).
//  - pnt staged once to LDS (bank-swizzled), single barrier; B-frags read
//    directly from L2; dynamic k-loop (no full unroll -> no spill).
//  - epilogue: 4-phase split-K combine into snum[16][.], MFMA dense
//    (wave = col-quarter), LN + swish; POOL emits column partials.
// ---------------------------------------------------------------------------
template <int DIN, int DOUT, bool POOL>
__global__ __launch_bounds__(256, 4) void fused_layer(
    const float4* __restrict__ pnt, const ushort* __restrict__ hT,
    const ushort* __restrict__ WT, const float* __restrict__ bias,
    const float* __restrict__ g, const float* __restrict__ be,
    ushort* __restrict__ hout, const float* __restrict__ mask,
    float* __restrict__ partial) {
  constexpr int NT = DIN / 16;
  constexpr int QJ = NPTS / 4;          // j span per wave
  constexpr int KS = QJ / 32;           // 16 k-steps
  constexpr int NCOL = DOUT / 64;       // dense col-tiles per wave
  constexpr int PS = DIN + 8;           // srow pitch (ushorts)
  constexpr int PN = DIN + 4;           // snum pitch (floats)
  constexpr int SPNT_B = NPTS * 16;     // 32 KB pnt (swizzled)
  constexpr int SNUM_B = 16 * PN * 4;
  constexpr int OFF_SROW = SNUM_B;
  constexpr int OFF_SDEN = OFF_SROW + 16 * PS * 2;  // [16]
  constexpr int OFF_SINV = OFF_SDEN + 64;           // [16]
  constexpr int OFF_SSTAT = OFF_SINV + 64;          // [16][4][2]
  constexpr int EPI_B = OFF_SSTAT + 512;
  constexpr int SMEM_B = SPNT_B > EPI_B ? SPNT_B : EPI_B;
  __shared__ __align__(16) char smem[SMEM_B];
  float4* sp = (float4*)smem;

  const int b = blockIdx.y;
  const int i0 = blockIdx.x * 16;
  const int tid = threadIdx.x;
  const int wv = tid >> 6, lane = tid & 63;
  const int m = lane & 15, q = lane >> 4;
  const float4* pb = pnt + (size_t)b * NPTS;
  const ushort* hb = hT + (size_t)b * DIN * NPTS;

  // stage pnt once, bank-swizzled: phys = (j&~31) | ((j&7)<<2) | ((j>>3)&3)
#pragma unroll
  for (int i = 0; i < NPTS / 256; i++) {
    const int j = i * 256 + tid;
    const int phys = (j & ~31) | (((j & 7) << 2) | ((j >> 3) & 3));
    sp[phys] = pb[j];
  }
  const float4 pi = pb[i0 + m];   // my A-row's point
  __syncthreads();

  f32x4 acc[NT];
#pragma unroll
  for (int nt = 0; nt < NT; nt++)
#pragma unroll
    for (int e = 0; e < 4; e++) acc[nt][e] = 0.f;
  float dacc = 0.f;

  const int jq = wv * QJ;   // this wave's j range

  for (int k = 0; k < KS; k++) {
    const int j0 = jq + k * 32;
    // B-fragments straight from L2: lane (m,q) reads 16B of row nt*16+m
    short8 bq[NT];
#pragma unroll
    for (int nt = 0; nt < NT; nt++)
      bq[nt] = *(const short8*)(hb + (size_t)(nt * 16 + m) * NPTS + j0 + q * 8);
    // w-gen from LDS pnt (covers the load latency)
    float wa[8];
#pragma unroll
    for (int jj = 0; jj < 8; jj++) {
      const float4 pj = sp[j0 + ((jj << 2) | q)];   // swizzled: conflict-free
      float a0 = pi.w + pj.w;
      a0 = fmaf(pi.x, pj.x, a0);
      a0 = fmaf(pi.y, pj.y, a0);
      a0 = fmaf(pi.z, pj.z, a0);
      wa[jj] = __builtin_amdgcn_exp2f(a0);   // exp(-dist)
      dacc += wa[jj];
    }
    unsigned int au[4];
#pragma unroll
    for (int p = 0; p < 4; p++) au[p] = pkbf(wa[2 * p], wa[2 * p + 1]);
    const short8 af = *(short8*)au;
#pragma unroll
    for (int nt = 0; nt < NT; nt++)
      acc[nt] = __builtin_amdgcn_mfma_f32_16x16x32_bf16(af, bq[nt], acc[nt], 0, 0, 0);
  }
  __syncthreads();   // all waves done with sp; epilogue aliases it

  // ---- 4-phase split-K combine in LDS ----
  float* snum = (float*)smem;                    // [16][PN]
  ushort* srow = (ushort*)(smem + OFF_SROW);     // [16][PS]
  float* sden = (float*)(smem + OFF_SDEN);
  float* sinv = (float*)(smem + OFF_SINV);
  float* sstat = (float*)(smem + OFF_SSTAT);     // [16][4][2]

  dacc += __shfl_xor(dacc, 16, 64);
  dacc += __shfl_xor(dacc, 32, 64);
  for (int p = 0; p < 4; p++) {
    if (wv == p) {
      if (p == 0) {
#pragma unroll
        for (int nt = 0; nt < NT; nt++)
#pragma unroll
          for (int r = 0; r < 4; r++)
            snum[(q * 4 + r) * PN + nt * 16 + m] = acc[nt][r];
        if (q == 0) sden[m] = dacc;
      } else {
#pragma unroll
        for (int nt = 0; nt < NT; nt++)
#pragma unroll
          for (int r = 0; r < 4; r++)
            snum[(q * 4 + r) * PN + nt * 16 + m] += acc[nt][r];
        if (q == 0) sden[m] += dacc;
      }
    }
    __syncthreads();
  }
  if (tid < 16) sinv[tid] = 1.0f / sden[tid];
  __syncthreads();
  for (int idx = tid; idx < 16 * (DIN / 2); idx += 256) {
    const int r = idx / (DIN / 2), c2 = idx % (DIN / 2);
    const float v0 = snum[r * PN + 2 * c2] * sinv[r];
    const float v1 = snum[r * PN + 2 * c2 + 1] * sinv[r];
    *(unsigned int*)&srow[r * PS + 2 * c2] = pkbf(v0, v1);
  }
  __syncthreads();

  // ---- dense via MFMA: 16 rows, wave = col-quarter ----
  const int ch = wv;
  short8 afrag[DIN / 32];
#pragma unroll
  for (int kt = 0; kt < DIN / 32; kt++)
    afrag[kt] = *(const short8*)&srow[m * PS + kt * 32 + q * 8];
  f32x4 oacc[NCOL];
#pragma unroll
  for (int c = 0; c < NCOL; c++)
#pragma unroll
    for (int e = 0; e < 4; e++) oacc[c][e] = 0.f;
#pragma unroll
  for (int c = 0; c < NCOL; c++) {
    const int n0 = (ch * NCOL + c) * 16;
#pragma unroll
    for (int kt = 0; kt < DIN / 32; kt++) {
      const short8 bfrag = *(const short8*)(WT + (size_t)(n0 + m) * DIN + kt * 32 + q * 8);
      oacc[c] = __builtin_amdgcn_mfma_f32_16x16x32_bf16(afrag[kt], bfrag, oacc[c], 0, 0, 0);
    }
  }

  // ---- LN stats across the 4 col-quarters via LDS ----
  float bcol[NCOL];
#pragma unroll
  for (int c = 0; c < NCOL; c++) bcol[c] = bias[(ch * NCOL + c) * 16 + m];
#pragma unroll
  for (int r = 0; r < 4; r++) {
    float m1 = 0.f, m2 = 0.f;
#pragma unroll
    for (int c = 0; c < NCOL; c++) {
      const float v = oacc[c][r] + bcol[c];
      m1 += v; m2 += v * v;
    }
#pragma unroll
    for (int off = 8; off > 0; off >>= 1) {
      m1 += __shfl_xor(m1, off, 64);
      m2 += __shfl_xor(m2, off, 64);
    }
    if (m == 0) {
      const int row = q * 4 + r;
      sstat[(row * 4 + ch) * 2 + 0] = m1;
      sstat[(row * 4 + ch) * 2 + 1] = m2;
    }
  }
  __syncthreads();

  ushort* lt = (ushort*)smem;   // [16][DOUT], aliases dead snum (TOUT path)
  float* spl = (float*)smem;    // [DOUT] (POOL path)
  float pacc[NCOL];
  if (POOL) {
#pragma unroll
    for (int c = 0; c < NCOL; c++) pacc[c] = 0.f;
  }
#pragma unroll
  for (int r = 0; r < 4; r++) {
    const int row = q * 4 + r;
    const float m1 = (sstat[(row * 4 + 0) * 2 + 0] + sstat[(row * 4 + 1) * 2 + 0]) +
                     (sstat[(row * 4 + 2) * 2 + 0] + sstat[(row * 4 + 3) * 2 + 0]);
    const float m2 = (sstat[(row * 4 + 0) * 2 + 1] + sstat[(row * 4 + 1) * 2 + 1]) +
                     (sstat[(row * 4 + 2) * 2 + 1] + sstat[(row * 4 + 3) * 2 + 1]);
    const float mu = m1 / DOUT;
    const float rstd = rsqrtf(m2 / DOUT - mu * mu + 1e-6f);
    float mval = 0.f;
    if (POOL) mval = mask[(size_t)b * NPTS + i0 + row];
#pragma unroll
    for (int c = 0; c < NCOL; c++) {
      const int dco = (ch * NCOL + c) * 16 + m;
      const float v = (oacc[c][r] + bcol[c] - mu) * rstd * g[dco] + be[dco];
      const float act = v / (1.0f + __expf(-v));
      if (POOL) pacc[c] = fmaf(act, mval, pacc[c]);
      else lt[row * DOUT + dco] = f2bf(act);
    }
  }
  if (POOL) {
#pragma unroll
    for (int c = 0; c < NCOL; c++) {
      float v = pacc[c];
      v += __shfl_xor(v, 16, 64);
      v += __shfl_xor(v, 32, 64);   // sum over q -> all 16 rows
      if (q == 0) spl[(ch * NCOL + c) * 16 + m] = v;
    }
    __syncthreads();
    if (tid < DOUT)
      partial[((size_t)b * (NPTS / 16) + blockIdx.x) * DOUT + tid] = spl[tid];
  } else {
    __syncthreads();
    if (tid < DOUT) {
      ushort tmp[16];
#pragma unroll
      for (int r = 0; r < 16; r++) tmp[r] = lt[r * DOUT + tid];
      ushort* dst = hout + ((size_t)b * DOUT + tid) * NPTS + i0;
      *(uint4*)dst = *(uint4*)&tmp[0];
      *(uint4*)(dst + 8) = *(uint4*)&tmp[8];
    }
  }
}

// ---------------------------------------------------------------------------
// readout: reduce 128 partial rows/batch, /count, Dense(256->128) with
// bf16 WzT[n][k] (contiguous dwordx4 loads, dot split across 2 half-waves).
// ---------------------------------------------------------------------------
__global__ __launch_bounds__(256) void readout_kernel(
    const float* __restrict__ partial, const float* __restrict__ mask,
    const ushort* __restrict__ WzT, const float* __restrict__ bz,
    float* __restrict__ out) {
  const int b = blockIdx.x;
  const int tid = threadIdx.x;
  const float* pb = partial + (size_t)b * (NPTS / 16) * 256;
  float s0 = 0.f, s1 = 0.f, s2 = 0.f, s3 = 0.f;
#pragma unroll 4
  for (int p = 0; p < NPTS / 16; p += 4) {
    s0 += pb[(size_t)(p + 0) * 256 + tid];
    s1 += pb[(size_t)(p + 1) * 256 + tid];
    s2 += pb[(size_t)(p + 2) * 256 + tid];
    s3 += pb[(size_t)(p + 3) * 256 + tid];
  }
  const float s = (s0 + s1) + (s2 + s3);
  const float* mb = mask + (size_t)b * NPTS;
  float c = 0.f;
  for (int n = tid; n < NPTS; n += 256) c += mb[n];
  __shared__ float red[256];
  red[tid] = c;
  __syncthreads();
  for (int off = 128; off > 0; off >>= 1) {
    if (tid < off) red[tid] += red[tid + off];
    __syncthreads();
  }
  const float cnt = fmaxf(red[0], 1.0f);
  __shared__ float gf[256];
  gf[tid] = s / cnt;
  __syncthreads();
  const int col = tid & 127, part = tid >> 7;   // split dot over 2 groups
  float z = 0.f;
  const ushort* wr = WzT + (size_t)col * 256 + part * 128;
  const float* gp = gf + part * 128;
#pragma unroll 4
  for (int d = 0; d < 128; d += 8) {
    const short8 w8 = *(const short8*)(wr + d);
#pragma unroll
    for (int e = 0; e < 8; e++)
      z = fmaf(gp[d + e], bf2f((ushort)w8[e]), z);
  }
  __shared__ float zred[256];
  zred[tid] = z;
  __syncthreads();
  if (tid < LATENT)
    out[(size_t)b * LATENT + tid] = bz[tid] + zred[tid] + zred[128 + tid];
}

// ---------------------------------------------------------------------------
extern "C" void kernel_launch(void* const* d_in, const int* in_sizes, int n_in,
                              void* d_out, int out_size, void* d_ws, size_t ws_size,
                              hipStream_t stream) {
  const float* x    = (const float*)d_in[0];
  const float* mask = (const float*)d_in[1];
  const float* W0   = (const float*)d_in[2];
  const float* b0   = (const float*)d_in[3];
  const float* g0   = (const float*)d_in[4];
  const float* be0  = (const float*)d_in[5];
  const float* W1   = (const float*)d_in[6];
  const float* b1   = (const float*)d_in[7];
  const float* g1   = (const float*)d_in[8];
  const float* be1  = (const float*)d_in[9];
  const float* W2   = (const float*)d_in[10];
  const float* b2   = (const float*)d_in[11];
  const float* g2   = (const float*)d_in[12];
  const float* be2  = (const float*)d_in[13];
  const float* Wz   = (const float*)d_in[14];
  const float* bz   = (const float*)d_in[15];
  float* out = (float*)d_out;

  // workspace layout (bytes, 16B-aligned regions)
  char* ws = (char*)d_ws;
  float4* pnt     = (float4*)(ws);             // 262144
  ushort* h1T     = (ushort*)(ws + 262144);    // 2097152
  ushort* h2T     = (ushort*)(ws + 2359296);   // 4194304
  float*  partial = (float*)(ws + 6553600);    // 8*128*256*4 = 1048576
  ushort* WT1     = (ushort*)(ws + 7602176);   // 16384
  ushort* WT2     = (ushort*)(ws + 7618560);   // 65536
  ushort* WzT     = (ushort*)(ws + 7684096);   // 65536
  // total ~7.75 MB

  // prep + all W transposes in one launch
  setup_kernel<<<dim3(26), dim3(256), 0, stream>>>(
      x, mask, pnt, W1, WT1, W2, WT2, Wz, WzT);

  // layer 0: agg (D=3) + dense 3->64 + LN + swish, fused
  layer0_kernel<<<dim3(NPTS / 64, BATCH), dim3(512), 0, stream>>>(
      pnt, W0, b0, g0, be0, h1T);

  // layer 1 (64 -> 128): fused MFMA agg + MFMA dense + LN + swish
  fused_layer<64, 128, false><<<dim3(NPTS / 16, BATCH), dim3(256), 0, stream>>>(
      pnt, h1T, WT1, b1, g1, be1, h2T, nullptr, nullptr);

  // layer 2 (128 -> 256): fused + masked-sum pooling
  fused_layer<128, 256, true><<<dim3(NPTS / 16, BATCH), dim3(256), 0, stream>>>(
      pnt, h2T, WT2, b2, g2, be2, nullptr, mask, partial);

  // readout
  readout_kernel<<<dim3(BATCH), dim3(256), 0, stream>>>(partial, mask, WzT, bz, out);
}

// Round 13
// 183.276 us; speedup vs baseline: 1.2273x; 1.2273x over previous
//
#include <hip/hip_runtime.h>
#include <hip/hip_bf16.h>

#define BATCH 8
#define NPTS 2048
#define LATENT 128

typedef __attribute__((ext_vector_type(8))) short short8;
typedef __attribute__((ext_vector_type(4))) float f32x4;

__device__ __forceinline__ ushort f2bf(float f) {
  unsigned int b = __float_as_uint(f);
  b += 0x7FFF + ((b >> 16) & 1);
  return (ushort)(b >> 16);
}
__device__ __forceinline__ float bf2f(ushort u) {
  return __uint_as_float(((unsigned int)u) << 16);
}
// packed bf16 convert (v_cvt_pk_bf16_f32 on gfx950), RNE — same as f2bf
__device__ __forceinline__ unsigned int pkbf(float a, float b) {
  __hip_bfloat162 h = __float22bfloat162_rn(make_float2(a, b));
  return *(unsigned int*)&h;
}

typedef unsigned int __attribute__((address_space(1))) gas_uint;
typedef unsigned int __attribute__((address_space(3))) las_uint;
__device__ __forceinline__ void gl_lds16(const void* g, void* l) {
  __builtin_amdgcn_global_load_lds((const gas_uint*)g, (las_uint*)l, 16, 0, 0);
}

// log2(e) and sqrt(2*log2(e)) — points are stored in exp2-space
#define L2E 1.4426950408889634f
#define SC2 1.6986436f

// ---------------------------------------------------------------------------
// setup: bid 0..7 = prep (centroid + pnt), 8..9 = WT1, 10..17 = WT2,
//        18..25 = WzT. WT[n][k] = bf16(W[k][n]).
// pnt[b][n] = (SC2*xc, -|xc|^2*L2E): pi.w+pj.w+dot(pi.xyz,pj.xyz) = -L2E*dist.
// ---------------------------------------------------------------------------
__device__ __forceinline__ void wtrans_tile(const float* __restrict__ W,
    ushort* __restrict__ WT, int K, int N, int n0, int k0, int tid) {
  __shared__ ushort s[64][72];
  for (int i = tid; i < 64 * 64; i += 256) {
    const int kl = i >> 6, nl = i & 63;
    s[kl][nl] = f2bf(W[(size_t)(k0 + kl) * N + n0 + nl]);
  }
  __syncthreads();
  for (int i = tid; i < 64 * 64; i += 256) {
    const int nl = i >> 6, kl = i & 63;
    WT[(size_t)(n0 + nl) * K + k0 + kl] = s[kl][nl];
  }
}

__global__ __launch_bounds__(256) void setup_kernel(const float* __restrict__ x,
    const float* __restrict__ mask, float4* __restrict__ pnt,
    const float* __restrict__ W1, ushort* __restrict__ WT1,
    const float* __restrict__ W2, ushort* __restrict__ WT2,
    const float* __restrict__ Wz, ushort* __restrict__ WzT) {
  const int bid = blockIdx.x;
  const int tid = threadIdx.x;
  if (bid >= 8) {
    if (bid < 10) wtrans_tile(W1, WT1, 64, 128, (bid - 8) * 64, 0, tid);
    else if (bid < 18) {
      const int idx = bid - 10;
      wtrans_tile(W2, WT2, 128, 256, (idx & 3) * 64, (idx >> 2) * 64, tid);
    } else {
      const int idx = bid - 18;
      wtrans_tile(Wz, WzT, 256, 128, (idx & 1) * 64, (idx >> 1) * 64, tid);
    }
    return;
  }
  const int b = bid;
  const float* xb = x + (size_t)b * NPTS * 3;
  const float* mb = mask + (size_t)b * NPTS;
  float s0 = 0.f, s1 = 0.f, s2 = 0.f, c = 0.f;
  for (int n = tid; n < NPTS; n += 256) {
    float m = mb[n];
    s0 += xb[n * 3 + 0] * m;
    s1 += xb[n * 3 + 1] * m;
    s2 += xb[n * 3 + 2] * m;
    c += m;
  }
  __shared__ float red[4][256];
  red[0][tid] = s0; red[1][tid] = s1; red[2][tid] = s2; red[3][tid] = c;
  __syncthreads();
  for (int off = 128; off > 0; off >>= 1) {
    if (tid < off) {
      red[0][tid] += red[0][tid + off];
      red[1][tid] += red[1][tid + off];
      red[2][tid] += red[2][tid + off];
      red[3][tid] += red[3][tid + off];
    }
    __syncthreads();
  }
  const float cnt = fmaxf(red[3][0], 1.0f);
  const float c0 = red[0][0] / cnt, c1 = red[1][0] / cnt, c2 = red[2][0] / cnt;
  float4* pb = pnt + (size_t)b * NPTS;
  for (int n = tid; n < NPTS; n += 256) {
    const float a0 = xb[n * 3 + 0] - c0;
    const float a1 = xb[n * 3 + 1] - c1;
    const float a2 = xb[n * 3 + 2] - c2;
    pb[n] = make_float4(a0 * SC2, a1 * SC2, a2 * SC2,
                        -(a0 * a0 + a1 * a1 + a2 * a2) * L2E);
  }
}

// ---------------------------------------------------------------------------
// layer 0 fused: aggregation (D=3, VALU, 8-way j-split) + dense 3->64 +
// LN + swish + transposed bf16 write h1T[b][d][n]. 64 rows/block, 512 thr.
// ---------------------------------------------------------------------------
__global__ __launch_bounds__(512) void layer0_kernel(
    const float4* __restrict__ pnt, const float* __restrict__ W,
    const float* __restrict__ bias, const float* __restrict__ g,
    const float* __restrict__ be, ushort* __restrict__ hout) {
  const int b = blockIdx.y;
  const int i0 = blockIdx.x * 64;
  const int tid = threadIdx.x;
  const int il = tid & 63, part = tid >> 6;   // 8 j-parts
  const float4* pb = pnt + (size_t)b * NPTS;
  const float4 pi = pb[i0 + il];
  float a0 = 0.f, a1 = 0.f, a2 = 0.f, dn = 0.f;
#pragma unroll 8
  for (int j = part * 256; j < part * 256 + 256; j++) {
    const float4 pj = pb[j];
    float arg = pi.w + pj.w;
    arg = fmaf(pi.x, pj.x, arg);
    arg = fmaf(pi.y, pj.y, arg);
    arg = fmaf(pi.z, pj.z, arg);
    const float w = __builtin_amdgcn_exp2f(arg);
    a0 = fmaf(w, pj.x, a0);
    a1 = fmaf(w, pj.y, a1);
    a2 = fmaf(w, pj.z, a2);
    dn += w;
  }
  __shared__ float4 sred[8][64];
  __shared__ float srow[64 * 3];
  __shared__ ushort lt[64][64];
  sred[part][il] = make_float4(a0, a1, a2, dn);
  __syncthreads();
  if (tid < 64) {
    float A0 = 0.f, A1 = 0.f, A2 = 0.f, DN = 0.f;
#pragma unroll
    for (int p = 0; p < 8; p++) {
      const float4 r = sred[p][tid];
      A0 += r.x; A1 += r.y; A2 += r.z; DN += r.w;
    }
    const float inv = 1.0f / (DN * SC2);   // undo SC2 scaling of xyz
    srow[tid * 3 + 0] = A0 * inv;
    srow[tid * 3 + 1] = A1 * inv;
    srow[tid * 3 + 2] = A2 * inv;
  }
  __syncthreads();
  const int wv = tid >> 6, lane = tid & 63;
  const float w0c = W[lane], w1c = W[64 + lane], w2c = W[128 + lane];
  const float gv = g[lane], bev = be[lane], bv = bias[lane];
#pragma unroll
  for (int r = 0; r < 8; r++) {
    const int row = wv * 8 + r;
    float o = bv;
    o = fmaf(srow[row * 3 + 0], w0c, o);
    o = fmaf(srow[row * 3 + 1], w1c, o);
    o = fmaf(srow[row * 3 + 2], w2c, o);
    float m1 = o, m2 = o * o;
#pragma unroll
    for (int off = 32; off > 0; off >>= 1) {
      m1 += __shfl_xor(m1, off, 64);
      m2 += __shfl_xor(m2, off, 64);
    }
    const float mu = m1 / 64.f;
    const float rstd = rsqrtf(m2 / 64.f - mu * mu + 1e-6f);
    const float v = (o - mu) * rstd * gv + bev;
    const float act = v / (1.0f + __expf(-v));
    lt[row][lane] = f2bf(act);
  }
  __syncthreads();
  if (tid < 64) {
    ushort tmp[64];
#pragma unroll
    for (int r = 0; r < 64; r++) tmp[r] = lt[r][tid];
    ushort* dst = hout + ((size_t)b * 64 + tid) * NPTS + i0;
#pragma unroll
    for (int c = 0; c < 8; c++)
      *(uint4*)(dst + c * 8) = *(uint4*)&tmp[c * 8];
  }
}

// ---------------------------------------------------------------------------
// fused_v5 (R8's measured-best layer-2 kernel, + packed bf16 cvt):
// 64 rows/block, 512 threads (8 waves = row-half x j-quarter), DMA
// global_load_lds double-buffered staging, one barrier per tile.
// ---------------------------------------------------------------------------
template <int DIN, int DOUT, bool POOL>
__global__ __launch_bounds__(512, 2) void fused_v5(
    const float4* __restrict__ pnt, const ushort* __restrict__ hT,
    const ushort* __restrict__ WT, const float* __restrict__ bias,
    const float* __restrict__ g, const float* __restrict__ be,
    ushort* __restrict__ hout, const float* __restrict__ mask,
    float* __restrict__ partial) {
  constexpr int NT = DIN / 16;
  constexpr int HALF = NPTS / 2;
  constexpr int TILES = HALF / 64;      // 16
  constexpr int NCOL = DOUT / 32;       // dense col-tiles per wave
  constexpr int PS = DIN + 8;           // srow pitch (ushorts)
  constexpr int PN = DIN + 4;           // snum pitch (floats)
  constexpr int SHT_B = 2 * 2 * DIN * 64 * 2;   // [buf][half][DIN][64] ushort
  constexpr int SPNT_B = 2 * 2 * 64 * 16;       // [buf][half][64] float4
  constexpr int LOOP_B = SHT_B + SPNT_B;
  constexpr int SNUM_B = 64 * PN * 4;           // [row][d] single slot
  constexpr int OFF_SROW = SNUM_B;              // [64][PS] ushort
  constexpr int OFF_SDEN = OFF_SROW + 64 * PS * 2;  // [64] float
  constexpr int OFF_SINV = OFF_SDEN + 256;      // [64] float
  constexpr int OFF_SSTAT = OFF_SINV + 256;     // [64][2][2] float
  constexpr int EPI_B = OFF_SSTAT + 1024;
  constexpr int SMEM_B = LOOP_B > EPI_B ? LOOP_B : EPI_B;
  __shared__ __align__(16) char smem[SMEM_B];
  ushort* sht = (ushort*)smem;
  float4* spnt = (float4*)(smem + SHT_B);

  const int b = blockIdx.y;
  const int i0 = blockIdx.x * 64;
  const int tid = threadIdx.x;
  const int wv = tid >> 6, lane = tid & 63;
  const int h = (wv >> 1) & 1;   // j half
  const int u = wv & 1;          // 32-j sub-tile
  const int rg = wv >> 2;        // row half (32 rows)
  const int m = lane & 15, q = lane >> 4;
  const float4* pb = pnt + (size_t)b * NPTS;
  const ushort* hb = hT + (size_t)b * DIN * NPTS;

  const float4 pi0 = pb[i0 + rg * 32 + m];        // A-rows +0..15
  const float4 pi1 = pb[i0 + rg * 32 + 16 + m];   // A-rows +16..31

  f32x4 acc0[NT], acc1[NT];
#pragma unroll
  for (int nt = 0; nt < NT; nt++)
#pragma unroll
    for (int e = 0; e < 4; e++) { acc0[nt][e] = 0.f; acc1[nt][e] = 0.f; }
  float dacc0 = 0.f, dacc1 = 0.f;

  constexpr int NCH = DIN / 32;            // sht DMA issues per wave
  const int srow8 = lane >> 3;
  const int scsrc = (lane & 7) ^ srow8;    // XOR-swizzled source chunk
  const int jsw = ((lane & 7) << 3) | (lane >> 3);  // spnt swizzle (involution)

  auto stage = [&](int t, int bf) {
    const int jb = t * 64;
#pragma unroll
    for (int i = 0; i < NCH; i++) {
      const int idx = wv * NCH + i;
      const int h2 = idx / (DIN / 8);
      const int oct = idx % (DIN / 8);
      const int row = oct * 8 + srow8;
      gl_lds16(hb + (size_t)row * NPTS + h2 * HALF + jb + scsrc * 8,
               sht + ((size_t)(bf * 2 + h2) * DIN + oct * 8) * 64);
    }
    if (wv == 0) {
#pragma unroll
      for (int h2 = 0; h2 < 2; h2++)
        gl_lds16(pb + h2 * HALF + jb + jsw, spnt + (bf * 2 + h2) * 64);
    }
  };

  stage(0, 0);
  __syncthreads();
  for (int t = 0; t < TILES; t++) {
    const int bf = t & 1;
    if (t + 1 < TILES) stage(t + 1, bf ^ 1);   // DMA into other buffer
    unsigned int au0[4], au1[4];
#pragma unroll
    for (int p = 0; p < 4; p++) {
      float wp[4];
#pragma unroll
      for (int e = 0; e < 2; e++) {
        const int jj = 2 * p + e;
        const float4 pj = spnt[(bf * 2 + h) * 64 + ((jj << 3) | (u * 4 + q))];
        float a0 = pi0.w + pj.w;
        a0 = fmaf(pi0.x, pj.x, a0);
        a0 = fmaf(pi0.y, pj.y, a0);
        a0 = fmaf(pi0.z, pj.z, a0);
        float a1 = pi1.w + pj.w;
        a1 = fmaf(pi1.x, pj.x, a1);
        a1 = fmaf(pi1.y, pj.y, a1);
        a1 = fmaf(pi1.z, pj.z, a1);
        wp[e] = __builtin_amdgcn_exp2f(a0);       // exp(-dist), rows 0..15
        wp[2 + e] = __builtin_amdgcn_exp2f(a1);   // rows 16..31
      }
      dacc0 += wp[0] + wp[1];
      dacc1 += wp[2] + wp[3];
      au0[p] = pkbf(wp[0], wp[1]);
      au1[p] = pkbf(wp[2], wp[3]);
    }
    const short8 af0 = *(short8*)au0;
    const short8 af1 = *(short8*)au1;
#pragma unroll
    for (int nt = 0; nt < NT; nt++) {
      const int d = nt * 16 + m;
      const short8 bfr = *(const short8*)
          &sht[((size_t)(bf * 2 + h) * DIN + d) * 64 + (((u * 4 + q) ^ (m & 7)) << 3)];
      acc0[nt] = __builtin_amdgcn_mfma_f32_16x16x32_bf16(af0, bfr, acc0[nt], 0, 0, 0);
      acc1[nt] = __builtin_amdgcn_mfma_f32_16x16x32_bf16(af1, bfr, acc1[nt], 0, 0, 0);
    }
    __syncthreads();
  }

  // ---- 1-slot 4-phase split-K combine in LDS (aliased over dead staging) --
  float* snum = (float*)smem;                    // [64][PN]
  ushort* srow = (ushort*)(smem + OFF_SROW);     // [64][PS]
  float* sden = (float*)(smem + OFF_SDEN);
  float* sinv = (float*)(smem + OFF_SINV);
  float* sstat = (float*)(smem + OFF_SSTAT);

  dacc0 += __shfl_xor(dacc0, 16, 64);
  dacc0 += __shfl_xor(dacc0, 32, 64);
  dacc1 += __shfl_xor(dacc1, 16, 64);
  dacc1 += __shfl_xor(dacc1, 32, 64);
  const int quarter = wv & 3;
  for (int p = 0; p < 4; p++) {
    if (quarter == p) {
      if (p == 0) {
#pragma unroll
        for (int nt = 0; nt < NT; nt++)
#pragma unroll
          for (int r = 0; r < 4; r++) {
            snum[(rg * 32 + q * 4 + r) * PN + nt * 16 + m] = acc0[nt][r];
            snum[(rg * 32 + 16 + q * 4 + r) * PN + nt * 16 + m] = acc1[nt][r];
          }
        if (q == 0) {
          sden[rg * 32 + m] = dacc0;
          sden[rg * 32 + 16 + m] = dacc1;
        }
      } else {
#pragma unroll
        for (int nt = 0; nt < NT; nt++)
#pragma unroll
          for (int r = 0; r < 4; r++) {
            snum[(rg * 32 + q * 4 + r) * PN + nt * 16 + m] += acc0[nt][r];
            snum[(rg * 32 + 16 + q * 4 + r) * PN + nt * 16 + m] += acc1[nt][r];
          }
        if (q == 0) {
          sden[rg * 32 + m] += dacc0;
          sden[rg * 32 + 16 + m] += dacc1;
        }
      }
    }
    __syncthreads();
  }
  if (tid < 64) sinv[tid] = 1.0f / sden[tid];
  __syncthreads();
  for (int idx = tid; idx < 64 * (DIN / 2); idx += 512) {
    const int r = idx / (DIN / 2), c2 = idx % (DIN / 2);
    const float v0 = snum[r * PN + 2 * c2] * sinv[r];
    const float v1 = snum[r * PN + 2 * c2 + 1] * sinv[r];
    *(unsigned int*)&srow[r * PS + 2 * c2] = pkbf(v0, v1);
  }
  __syncthreads();

  // ---- dense via MFMA: rows (wv>>1)*16.., col-half (wv&1) ----
  const int rg2 = wv >> 1, ch = wv & 1;
  short8 afrag[DIN / 32];
#pragma unroll
  for (int kt = 0; kt < DIN / 32; kt++)
    afrag[kt] = *(const short8*)&srow[(rg2 * 16 + m) * PS + kt * 32 + q * 8];
  f32x4 oacc[NCOL];
#pragma unroll
  for (int c = 0; c < NCOL; c++)
#pragma unroll
    for (int e = 0; e < 4; e++) oacc[c][e] = 0.f;
#pragma unroll
  for (int c = 0; c < NCOL; c++) {
    const int n0 = (ch * NCOL + c) * 16;
#pragma unroll
    for (int kt = 0; kt < DIN / 32; kt++) {
      const short8 bfrag = *(const short8*)(WT + (size_t)(n0 + m) * DIN + kt * 32 + q * 8);
      oacc[c] = __builtin_amdgcn_mfma_f32_16x16x32_bf16(afrag[kt], bfrag, oacc[c], 0, 0, 0);
    }
  }

  // ---- LN stats across both col-halves via LDS ----
  float bcol[NCOL];
#pragma unroll
  for (int c = 0; c < NCOL; c++) bcol[c] = bias[(ch * NCOL + c) * 16 + m];
#pragma unroll
  for (int r = 0; r < 4; r++) {
    float m1 = 0.f, m2 = 0.f;
#pragma unroll
    for (int c = 0; c < NCOL; c++) {
      const float v = oacc[c][r] + bcol[c];
      m1 += v; m2 += v * v;
    }
#pragma unroll
    for (int off = 8; off > 0; off >>= 1) {
      m1 += __shfl_xor(m1, off, 64);
      m2 += __shfl_xor(m2, off, 64);
    }
    if (m == 0) {
      const int row = rg2 * 16 + q * 4 + r;
      sstat[(row * 2 + ch) * 2 + 0] = m1;
      sstat[(row * 2 + ch) * 2 + 1] = m2;
    }
  }
  __syncthreads();

  ushort* lt = (ushort*)smem;   // [64][DOUT], aliases dead snum (TOUT path)
  float* spl = (float*)smem;    // [4][DOUT] (POOL path)
  float pacc[NCOL];
  if (POOL) {
#pragma unroll
    for (int c = 0; c < NCOL; c++) pacc[c] = 0.f;
  }
#pragma unroll
  for (int r = 0; r < 4; r++) {
    const int row = rg2 * 16 + q * 4 + r;
    const float m1 = sstat[(row * 2 + 0) * 2 + 0] + sstat[(row * 2 + 1) * 2 + 0];
    const float m2 = sstat[(row * 2 + 0) * 2 + 1] + sstat[(row * 2 + 1) * 2 + 1];
    const float mu = m1 / DOUT;
    const float rstd = rsqrtf(m2 / DOUT - mu * mu + 1e-6f);
    float mval = 0.f;
    if (POOL) mval = mask[(size_t)b * NPTS + i0 + row];
#pragma unroll
    for (int c = 0; c < NCOL; c++) {
      const int dco = (ch * NCOL + c) * 16 + m;
      const float v = (oacc[c][r] + bcol[c] - mu) * rstd * g[dco] + be[dco];
      const float act = v / (1.0f + __expf(-v));
      if (POOL) pacc[c] = fmaf(act, mval, pacc[c]);
      else lt[row * DOUT + dco] = f2bf(act);
    }
  }
  if (POOL) {
#pragma unroll
    for (int c = 0; c < NCOL; c++) {
      float v = pacc[c];
      v += __shfl_xor(v, 16, 64);
      v += __shfl_xor(v, 32, 64);   // sum over q -> this wave's 16 rows
      if (q == 0) spl[rg2 * DOUT + (ch * NCOL + c) * 16 + m] = v;
    }
    __syncthreads();
    if (tid < DOUT)
      partial[((size_t)b * (NPTS / 64) + blockIdx.x) * DOUT + tid] =
          (spl[tid] + spl[DOUT + tid]) + (spl[2 * DOUT + tid] + spl[3 * DOUT + tid]);
  } else {
    __syncthreads();
    if (tid < DOUT) {
      ushort tmp[64];
#pragma unroll
      for (int r = 0; r < 64; r++) tmp[r] = lt[r * DOUT + tid];
      ushort* dst = hout + ((size_t)b * DOUT + tid) * NPTS + i0;
#pragma unroll
      for (int c = 0; c < 8; c++)
        *(uint4*)(dst + c * 8) = *(uint4*)&tmp[c * 8];
    }
  }
}

// ---------------------------------------------------------------------------
// fused_v6 (R9's layer-1 kernel): 32 rows/block, 256 threads, 4 waves =
// {j-half}x{j-sub32}; each wave owns all 32 rows; DMA double-buffer staging.
// ---------------------------------------------------------------------------
template <int DIN, int DOUT, bool POOL, int MINW>
__global__ __launch_bounds__(256, MINW) void fused_v6(
    const float4* __restrict__ pnt, const ushort* __restrict__ hT,
    const ushort* __restrict__ WT, const float* __restrict__ bias,
    const float* __restrict__ g, const float* __restrict__ be,
    ushort* __restrict__ hout, const float* __restrict__ mask,
    float* __restrict__ partial) {
  constexpr int NT = DIN / 16;
  constexpr int HALF = NPTS / 2;
  constexpr int TILES = HALF / 64;      // 16
  constexpr int NCOL = DOUT / 32;       // dense col-tiles per wave
  constexpr int PS = DIN + 8;           // srow pitch (ushorts)
  constexpr int PN = DIN + 4;           // snum pitch (floats)
  constexpr int SHT_B = 2 * 2 * DIN * 64 * 2;   // [buf][half][DIN][64] ushort
  constexpr int SPNT_B = 2 * 2 * 64 * 16;       // [buf][half][64] float4
  constexpr int LOOP_B = SHT_B + SPNT_B;
  constexpr int SNUM_B = 32 * PN * 4;           // [row][d] single slot
  constexpr int OFF_SROW = SNUM_B;              // [32][PS] ushort
  constexpr int OFF_SDEN = OFF_SROW + 32 * PS * 2;  // [32] float
  constexpr int OFF_SINV = OFF_SDEN + 128;      // [32] float
  constexpr int OFF_SSTAT = OFF_SINV + 128;     // [32][2][2] float
  constexpr int EPI_B = OFF_SSTAT + 512;
  constexpr int SMEM_B = LOOP_B > EPI_B ? LOOP_B : EPI_B;
  __shared__ __align__(16) char smem[SMEM_B];
  ushort* sht = (ushort*)smem;
  float4* spnt = (float4*)(smem + SHT_B);

  const int b = blockIdx.y;
  const int i0 = blockIdx.x * 32;
  const int tid = threadIdx.x;
  const int wv = tid >> 6, lane = tid & 63;
  const int h = wv >> 1;   // j half
  const int u = wv & 1;    // 32-j sub-tile
  const int m = lane & 15, q = lane >> 4;
  const float4* pb = pnt + (size_t)b * NPTS;
  const ushort* hb = hT + (size_t)b * DIN * NPTS;

  const float4 pi0 = pb[i0 + m];        // A-rows 0..15
  const float4 pi1 = pb[i0 + 16 + m];   // A-rows 16..31

  f32x4 acc0[NT], acc1[NT];
#pragma unroll
  for (int nt = 0; nt < NT; nt++)
#pragma unroll
    for (int e = 0; e < 4; e++) { acc0[nt][e] = 0.f; acc1[nt][e] = 0.f; }
  float dacc0 = 0.f, dacc1 = 0.f;

  constexpr int NCH = DIN / 16;            // sht DMA issues per wave
  const int srow8 = lane >> 3;
  const int scsrc = (lane & 7) ^ srow8;    // XOR-swizzled source chunk
  const int jsw = ((lane & 7) << 3) | (lane >> 3);  // spnt swizzle (involution)

  auto stage = [&](int t, int bf) {
    const int jb = t * 64;
#pragma unroll
    for (int i = 0; i < NCH; i++) {
      const int idx = wv * NCH + i;
      const int h2 = idx / (DIN / 8);
      const int oct = idx % (DIN / 8);
      const int row = oct * 8 + srow8;
      gl_lds16(hb + (size_t)row * NPTS + h2 * HALF + jb + scsrc * 8,
               sht + ((size_t)(bf * 2 + h2) * DIN + oct * 8) * 64);
    }
    if (wv == 0) {
#pragma unroll
      for (int h2 = 0; h2 < 2; h2++)
        gl_lds16(pb + h2 * HALF + jb + jsw, spnt + (bf * 2 + h2) * 64);
    }
  };

  stage(0, 0);
  __syncthreads();
  for (int t = 0; t < TILES; t++) {
    const int bf = t & 1;
    if (t + 1 < TILES) stage(t + 1, bf ^ 1);   // DMA into other buffer
    float w0a[8], w1a[8];
#pragma unroll
    for (int jj = 0; jj < 8; jj++) {
      const float4 pj = spnt[(bf * 2 + h) * 64 + ((jj << 3) | (u * 4 + q))];
      float a0 = pi0.w + pj.w;
      a0 = fmaf(pi0.x, pj.x, a0);
      a0 = fmaf(pi0.y, pj.y, a0);
      a0 = fmaf(pi0.z, pj.z, a0);
      float a1 = pi1.w + pj.w;
      a1 = fmaf(pi1.x, pj.x, a1);
      a1 = fmaf(pi1.y, pj.y, a1);
      a1 = fmaf(pi1.z, pj.z, a1);
      w0a[jj] = __builtin_amdgcn_exp2f(a0);   // exp(-dist)
      w1a[jj] = __builtin_amdgcn_exp2f(a1);
      dacc0 += w0a[jj]; dacc1 += w1a[jj];
    }
    unsigned int au0[4], au1[4];
#pragma unroll
    for (int p = 0; p < 4; p++) {
      au0[p] = pkbf(w0a[2 * p], w0a[2 * p + 1]);
      au1[p] = pkbf(w1a[2 * p], w1a[2 * p + 1]);
    }
    const short8 af0 = *(short8*)au0;
    const short8 af1 = *(short8*)au1;
#pragma unroll
    for (int nt = 0; nt < NT; nt++) {
      const int d = nt * 16 + m;
      const short8 bfr = *(const short8*)
          &sht[((size_t)(bf * 2 + h) * DIN + d) * 64 + (((u * 4 + q) ^ (m & 7)) << 3)];
      acc0[nt] = __builtin_amdgcn_mfma_f32_16x16x32_bf16(af0, bfr, acc0[nt], 0, 0, 0);
      acc1[nt] = __builtin_amdgcn_mfma_f32_16x16x32_bf16(af1, bfr, acc1[nt], 0, 0, 0);
    }
    __syncthreads();
  }

  // ---- 1-slot 4-phase split-K combine in LDS (aliased over dead staging) --
  float* snum = (float*)smem;                    // [32][PN]
  ushort* srow = (ushort*)(smem + OFF_SROW);     // [32][PS]
  float* sden = (float*)(smem + OFF_SDEN);
  float* sinv = (float*)(smem + OFF_SINV);
  float* sstat = (float*)(smem + OFF_SSTAT);

  dacc0 += __shfl_xor(dacc0, 16, 64);
  dacc0 += __shfl_xor(dacc0, 32, 64);
  dacc1 += __shfl_xor(dacc1, 16, 64);
  dacc1 += __shfl_xor(dacc1, 32, 64);
  for (int p = 0; p < 4; p++) {
    if (wv == p) {
      if (p == 0) {
#pragma unroll
        for (int nt = 0; nt < NT; nt++)
#pragma unroll
          for (int r = 0; r < 4; r++) {
            snum[(q * 4 + r) * PN + nt * 16 + m] = acc0[nt][r];
            snum[(16 + q * 4 + r) * PN + nt * 16 + m] = acc1[nt][r];
          }
        if (q == 0) { sden[m] = dacc0; sden[16 + m] = dacc1; }
      } else {
#pragma unroll
        for (int nt = 0; nt < NT; nt++)
#pragma unroll
          for (int r = 0; r < 4; r++) {
            snum[(q * 4 + r) * PN + nt * 16 + m] += acc0[nt][r];
            snum[(16 + q * 4 + r) * PN + nt * 16 + m] += acc1[nt][r];
          }
        if (q == 0) { sden[m] += dacc0; sden[16 + m] += dacc1; }
      }
    }
    __syncthreads();
  }
  if (tid < 32) sinv[tid] = 1.0f / sden[tid];
  __syncthreads();
  for (int idx = tid; idx < 32 * (DIN / 2); idx += 256) {
    const int r = idx / (DIN / 2), c2 = idx % (DIN / 2);
    const float v0 = snum[r * PN + 2 * c2] * sinv[r];
    const float v1 = snum[r * PN + 2 * c2 + 1] * sinv[r];
    *(unsigned int*)&srow[r * PS + 2 * c2] = pkbf(v0, v1);
  }
  __syncthreads();

  // ---- dense via MFMA: rows (wv>>1)*16.., col-half (wv&1) ----
  const int rg2 = wv >> 1, ch = wv & 1;
  short8 afrag[DIN / 32];
#pragma unroll
  for (int kt = 0; kt < DIN / 32; kt++)
    afrag[kt] = *(const short8*)&srow[(rg2 * 16 + m) * PS + kt * 32 + q * 8];
  f32x4 oacc[NCOL];
#pragma unroll
  for (int c = 0; c < NCOL; c++)
#pragma unroll
    for (int e = 0; e < 4; e++) oacc[c][e] = 0.f;
#pragma unroll
  for (int c = 0; c < NCOL; c++) {
    const int n0 = (ch * NCOL + c) * 16;
#pragma unroll
    for (int kt = 0; kt < DIN / 32; kt++) {
      const short8 bfrag = *(const short8*)(WT + (size_t)(n0 + m) * DIN + kt * 32 + q * 8);
      oacc[c] = __builtin_amdgcn_mfma_f32_16x16x32_bf16(afrag[kt], bfrag, oacc[c], 0, 0, 0);
    }
  }

  // ---- LN stats across both col-halves via LDS ----
  float bcol[NCOL];
#pragma unroll
  for (int c = 0; c < NCOL; c++) bcol[c] = bias[(ch * NCOL + c) * 16 + m];
#pragma unroll
  for (int r = 0; r < 4; r++) {
    float m1 = 0.f, m2 = 0.f;
#pragma unroll
    for (int c = 0; c < NCOL; c++) {
      const float v = oacc[c][r] + bcol[c];
      m1 += v; m2 += v * v;
    }
#pragma unroll
    for (int off = 8; off > 0; off >>= 1) {
      m1 += __shfl_xor(m1, off, 64);
      m2 += __shfl_xor(m2, off, 64);
    }
    if (m == 0) {
      const int row = rg2 * 16 + q * 4 + r;
      sstat[(row * 2 + ch) * 2 + 0] = m1;
      sstat[(row * 2 + ch) * 2 + 1] = m2;
    }
  }
  __syncthreads();

  ushort* lt = (ushort*)smem;   // [32][DOUT], aliases dead snum (TOUT path)
  float* spl = (float*)smem;    // [2][DOUT] (POOL path)
  float pacc[NCOL];
  if (POOL) {
#pragma unroll
    for (int c = 0; c < NCOL; c++) pacc[c] = 0.f;
  }
#pragma unroll
  for (int r = 0; r < 4; r++) {
    const int row = rg2 * 16 + q * 4 + r;
    const float m1 = sstat[(row * 2 + 0) * 2 + 0] + sstat[(row * 2 + 1) * 2 + 0];
    const float m2 = sstat[(row * 2 + 0) * 2 + 1] + sstat[(row * 2 + 1) * 2 + 1];
    const float mu = m1 / DOUT;
    const float rstd = rsqrtf(m2 / DOUT - mu * mu + 1e-6f);
    float mval = 0.f;
    if (POOL) mval = mask[(size_t)b * NPTS + i0 + row];
#pragma unroll
    for (int c = 0; c < NCOL; c++) {
      const int dco = (ch * NCOL + c) * 16 + m;
      const float v = (oacc[c][r] + bcol[c] - mu) * rstd * g[dco] + be[dco];
      const float act = v / (1.0f + __expf(-v));
      if (POOL) pacc[c] = fmaf(act, mval, pacc[c]);
      else lt[row * DOUT + dco] = f2bf(act);
    }
  }
  if (POOL) {
#pragma unroll
    for (int c = 0; c < NCOL; c++) {
      float v = pacc[c];
      v += __shfl_xor(v, 16, 64);
      v += __shfl_xor(v, 32, 64);   // sum over q -> this wave's 16 rows
      if (q == 0) spl[rg2 * DOUT + (ch * NCOL + c) * 16 + m] = v;
    }
    __syncthreads();
    if (tid < DOUT)
      partial[((size_t)b * (NPTS / 32) + blockIdx.x) * DOUT + tid] =
          spl[tid] + spl[DOUT + tid];
  } else {
    __syncthreads();
    if (tid < DOUT) {
      ushort tmp[32];
#pragma unroll
      for (int r = 0; r < 32; r++) tmp[r] = lt[r * DOUT + tid];
      ushort* dst = hout + ((size_t)b * DOUT + tid) * NPTS + i0;
#pragma unroll
      for (int c = 0; c < 4; c++)
        *(uint4*)(dst + c * 8) = *(uint4*)&tmp[c * 8];
    }
  }
}

// ---------------------------------------------------------------------------
// readout: reduce 32 partial rows/batch, /count, Dense(256->128) with
// bf16 WzT[n][k] (contiguous dwordx4 loads, dot split across 2 half-waves).
// ---------------------------------------------------------------------------
__global__ __launch_bounds__(256) void readout_kernel(
    const float* __restrict__ partial, const float* __restrict__ mask,
    const ushort* __restrict__ WzT, const float* __restrict__ bz,
    float* __restrict__ out) {
  const int b = blockIdx.x;
  const int tid = threadIdx.x;
  const float* pb = partial + (size_t)b * (NPTS / 64) * 256;
  float s0 = 0.f, s1 = 0.f, s2 = 0.f, s3 = 0.f;
#pragma unroll
  for (int p = 0; p < NPTS / 64; p += 4) {
    s0 += pb[(size_t)(p + 0) * 256 + tid];
    s1 += pb[(size_t)(p + 1) * 256 + tid];
    s2 += pb[(size_t)(p + 2) * 256 + tid];
    s3 += pb[(size_t)(p + 3) * 256 + tid];
  }
  const float s = (s0 + s1) + (s2 + s3);
  const float* mb = mask + (size_t)b * NPTS;
  float c = 0.f;
  for (int n = tid; n < NPTS; n += 256) c += mb[n];
  __shared__ float red[256];
  red[tid] = c;
  __syncthreads();
  for (int off = 128; off > 0; off >>= 1) {
    if (tid < off) red[tid] += red[tid + off];
    __syncthreads();
  }
  const float cnt = fmaxf(red[0], 1.0f);
  __shared__ float gf[256];
  gf[tid] = s / cnt;
  __syncthreads();
  const int col = tid & 127, part = tid >> 7;   // split dot over 2 groups
  float z = 0.f;
  const ushort* wr = WzT + (size_t)col * 256 + part * 128;
  const float* gp = gf + part * 128;
#pragma unroll 4
  for (int d = 0; d < 128; d += 8) {
    const short8 w8 = *(const short8*)(wr + d);
#pragma unroll
    for (int e = 0; e < 8; e++)
      z = fmaf(gp[d + e], bf2f((ushort)w8[e]), z);
  }
  __shared__ float zred[256];
  zred[tid] = z;
  __syncthreads();
  if (tid < LATENT)
    out[(size_t)b * LATENT + tid] = bz[tid] + zred[tid] + zred[128 + tid];
}

// ---------------------------------------------------------------------------
extern "C" void kernel_launch(void* const* d_in, const int* in_sizes, int n_in,
                              void* d_out, int out_size, void* d_ws, size_t ws_size,
                              hipStream_t stream) {
  const float* x    = (const float*)d_in[0];
  const float* mask = (const float*)d_in[1];
  const float* W0   = (const float*)d_in[2];
  const float* b0   = (const float*)d_in[3];
  const float* g0   = (const float*)d_in[4];
  const float* be0  = (const float*)d_in[5];
  const float* W1   = (const float*)d_in[6];
  const float* b1   = (const float*)d_in[7];
  const float* g1   = (const float*)d_in[8];
  const float* be1  = (const float*)d_in[9];
  const float* W2   = (const float*)d_in[10];
  const float* b2   = (const float*)d_in[11];
  const float* g2   = (const float*)d_in[12];
  const float* be2  = (const float*)d_in[13];
  const float* Wz   = (const float*)d_in[14];
  const float* bz   = (const float*)d_in[15];
  float* out = (float*)d_out;

  // workspace layout (bytes, 16B-aligned regions)
  char* ws = (char*)d_ws;
  float4* pnt     = (float4*)(ws);             // 262144
  ushort* h1T     = (ushort*)(ws + 262144);    // 2097152
  ushort* h2T     = (ushort*)(ws + 2359296);   // 4194304
  float*  partial = (float*)(ws + 6553600);    // 8*32*256*4 = 262144
  ushort* WT1     = (ushort*)(ws + 6815744);   // 16384
  ushort* WT2     = (ushort*)(ws + 6832128);   // 65536
  ushort* WzT     = (ushort*)(ws + 6897664);   // 65536
  // total ~6.96 MB

  // prep + all W transposes in one launch
  setup_kernel<<<dim3(26), dim3(256), 0, stream>>>(
      x, mask, pnt, W1, WT1, W2, WT2, Wz, WzT);

  // layer 0: agg (D=3) + dense 3->64 + LN + swish, fused
  layer0_kernel<<<dim3(NPTS / 64, BATCH), dim3(512), 0, stream>>>(
      pnt, W0, b0, g0, be0, h1T);

  // layer 1 (64 -> 128): v6 (32-row/256-thr, best measured for DIN=64)
  fused_v6<64, 128, false, 4><<<dim3(NPTS / 32, BATCH), dim3(256), 0, stream>>>(
      pnt, h1T, WT1, b1, g1, be1, h2T, nullptr, nullptr);

  // layer 2 (128 -> 256): v5 (64-row/512-thr, best measured for DIN=128)
  fused_v5<128, 256, true><<<dim3(NPTS / 64, BATCH), dim3(512), 0, stream>>>(
      pnt, h2T, WT2, b2, g2, be2, nullptr, mask, partial);

  // readout
  readout_kernel<<<dim3(BATCH), dim3(256), 0, stream>>>(partial, mask, WzT, bz, out);
}

// Round 14
// 179.127 us; speedup vs baseline: 1.2557x; 1.0232x over previous
//
#include <hip/hip_runtime.h>
#include <hip/hip_bf16.h>

#define BATCH 8
#define NPTS 2048
#define LATENT 128

typedef __attribute__((ext_vector_type(8))) short short8;
typedef __attribute__((ext_vector_type(4))) float f32x4;

__device__ __forceinline__ ushort f2bf(float f) {
  unsigned int b = __float_as_uint(f);
  b += 0x7FFF + ((b >> 16) & 1);
  return (ushort)(b >> 16);
}
__device__ __forceinline__ float bf2f(ushort u) {
  return __uint_as_float(((unsigned int)u) << 16);
}
// packed bf16 convert (v_cvt_pk_bf16_f32 on gfx950), RNE — same as f2bf
__device__ __forceinline__ unsigned int pkbf(float a, float b) {
  __hip_bfloat162 h = __float22bfloat162_rn(make_float2(a, b));
  return *(unsigned int*)&h;
}

typedef unsigned int __attribute__((address_space(1))) gas_uint;
typedef unsigned int __attribute__((address_space(3))) las_uint;
__device__ __forceinline__ void gl_lds16(const void* g, void* l) {
  __builtin_amdgcn_global_load_lds((const gas_uint*)g, (las_uint*)l, 16, 0, 0);
}

// log2(e) and sqrt(2*log2(e)) — points are stored in exp2-space
#define L2E 1.4426950408889634f
#define SC2 1.6986436f

// ---------------------------------------------------------------------------
// setup: bid 0..7 = prep (centroid + pnt), 8..9 = WT1, 10..17 = WT2,
//        18..25 = WzT. WT[n][k] = bf16(W[k][n]).
// pnt[b][n] = (SC2*xc, -|xc|^2*L2E): pi.w+pj.w+dot(pi.xyz,pj.xyz) = -L2E*dist.
// ---------------------------------------------------------------------------
__device__ __forceinline__ void wtrans_tile(const float* __restrict__ W,
    ushort* __restrict__ WT, int K, int N, int n0, int k0, int tid) {
  __shared__ ushort s[64][72];
  for (int i = tid; i < 64 * 64; i += 256) {
    const int kl = i >> 6, nl = i & 63;
    s[kl][nl] = f2bf(W[(size_t)(k0 + kl) * N + n0 + nl]);
  }
  __syncthreads();
  for (int i = tid; i < 64 * 64; i += 256) {
    const int nl = i >> 6, kl = i & 63;
    WT[(size_t)(n0 + nl) * K + k0 + kl] = s[kl][nl];
  }
}

__global__ __launch_bounds__(256) void setup_kernel(const float* __restrict__ x,
    const float* __restrict__ mask, float4* __restrict__ pnt,
    const float* __restrict__ W1, ushort* __restrict__ WT1,
    const float* __restrict__ W2, ushort* __restrict__ WT2,
    const float* __restrict__ Wz, ushort* __restrict__ WzT) {
  const int bid = blockIdx.x;
  const int tid = threadIdx.x;
  if (bid >= 8) {
    if (bid < 10) wtrans_tile(W1, WT1, 64, 128, (bid - 8) * 64, 0, tid);
    else if (bid < 18) {
      const int idx = bid - 10;
      wtrans_tile(W2, WT2, 128, 256, (idx & 3) * 64, (idx >> 2) * 64, tid);
    } else {
      const int idx = bid - 18;
      wtrans_tile(Wz, WzT, 256, 128, (idx & 1) * 64, (idx >> 1) * 64, tid);
    }
    return;
  }
  const int b = bid;
  const float* xb = x + (size_t)b * NPTS * 3;
  const float* mb = mask + (size_t)b * NPTS;
  float s0 = 0.f, s1 = 0.f, s2 = 0.f, c = 0.f;
  for (int n = tid; n < NPTS; n += 256) {
    float m = mb[n];
    s0 += xb[n * 3 + 0] * m;
    s1 += xb[n * 3 + 1] * m;
    s2 += xb[n * 3 + 2] * m;
    c += m;
  }
  __shared__ float red[4][256];
  red[0][tid] = s0; red[1][tid] = s1; red[2][tid] = s2; red[3][tid] = c;
  __syncthreads();
  for (int off = 128; off > 0; off >>= 1) {
    if (tid < off) {
      red[0][tid] += red[0][tid + off];
      red[1][tid] += red[1][tid + off];
      red[2][tid] += red[2][tid + off];
      red[3][tid] += red[3][tid + off];
    }
    __syncthreads();
  }
  const float cnt = fmaxf(red[3][0], 1.0f);
  const float c0 = red[0][0] / cnt, c1 = red[1][0] / cnt, c2 = red[2][0] / cnt;
  float4* pb = pnt + (size_t)b * NPTS;
  for (int n = tid; n < NPTS; n += 256) {
    const float a0 = xb[n * 3 + 0] - c0;
    const float a1 = xb[n * 3 + 1] - c1;
    const float a2 = xb[n * 3 + 2] - c2;
    pb[n] = make_float4(a0 * SC2, a1 * SC2, a2 * SC2,
                        -(a0 * a0 + a1 * a1 + a2 * a2) * L2E);
  }
}

// ---------------------------------------------------------------------------
// wgen: materialize W[b][jt][i] (bf16, MFMA-A-ready tiled layout: short8 at
// [jt][i] = w(i, jt*8..jt*8+8)) + part[js][b][i] = (Σw·u_j, Σw) over the
// block's j-range. pj loads are wave-uniform -> scalar s_load; pi per lane.
// grid (8 j-splits, 16 i-tiles, 8 batches), 128 threads.
// ---------------------------------------------------------------------------
__global__ __launch_bounds__(128) void wgen_kernel(
    const float4* __restrict__ pnt, ushort* __restrict__ Wt,
    float4* __restrict__ part) {
  const int js = blockIdx.x;
  const int it = blockIdx.y;
  const int b = blockIdx.z;
  const int tid = threadIdx.x;
  const int i = it * 128 + tid;
  const float4* pb = pnt + (size_t)b * NPTS;
  const float4 pi = pb[i];
  float a0 = 0.f, a1 = 0.f, a2 = 0.f, dn = 0.f;
  ushort* wb = Wt + (size_t)b * 256 * NPTS * 8;
  for (int jt = js * 32; jt < js * 32 + 32; jt++) {
    unsigned int au[4];
#pragma unroll
    for (int e2 = 0; e2 < 4; e2++) {
      float wv0, wv1;
      {
        const float4 pj = pb[jt * 8 + e2 * 2 + 0];   // uniform -> s_load
        float arg = pi.w + pj.w;
        arg = fmaf(pi.x, pj.x, arg);
        arg = fmaf(pi.y, pj.y, arg);
        arg = fmaf(pi.z, pj.z, arg);
        wv0 = __builtin_amdgcn_exp2f(arg);
        dn += wv0;
        a0 = fmaf(wv0, pj.x, a0);
        a1 = fmaf(wv0, pj.y, a1);
        a2 = fmaf(wv0, pj.z, a2);
      }
      {
        const float4 pj = pb[jt * 8 + e2 * 2 + 1];
        float arg = pi.w + pj.w;
        arg = fmaf(pi.x, pj.x, arg);
        arg = fmaf(pi.y, pj.y, arg);
        arg = fmaf(pi.z, pj.z, arg);
        wv1 = __builtin_amdgcn_exp2f(arg);
        dn += wv1;
        a0 = fmaf(wv1, pj.x, a0);
        a1 = fmaf(wv1, pj.y, a1);
        a2 = fmaf(wv1, pj.z, a2);
      }
      au[e2] = pkbf(wv0, wv1);
    }
    *(uint4*)(wb + ((size_t)jt * NPTS + i) * 8) = *(uint4*)au;
  }
  part[(size_t)js * (BATCH * NPTS) + (size_t)b * NPTS + i] =
      make_float4(a0, a1, a2, dn);
}

// ---------------------------------------------------------------------------
// mlp0: combine wgen partials -> hagg0 row (/den, /SC2) -> dense 3->64 ->
// LN -> swish -> transposed bf16 h1T[b][d][n]. 16 rows/block, 256 thr.
// ---------------------------------------------------------------------------
__global__ __launch_bounds__(256) void mlp0_kernel(
    const float4* __restrict__ part, const float* __restrict__ W,
    const float* __restrict__ bias, const float* __restrict__ g,
    const float* __restrict__ be, ushort* __restrict__ hout) {
  constexpr int DIN = 3, DOUT = 64;
  const int tid = threadIdx.x;
  const int wv = tid >> 6, lane = tid & 63;
  const int r0 = blockIdx.x * 16;
  const int bb = r0 / NPTS;
  const int nn = r0 % NPTS;
  __shared__ float srow[16 * DIN];
  if (tid < 16) {
    float4 s = part[(size_t)bb * NPTS + nn + tid];
#pragma unroll
    for (int p = 1; p < 8; p++) {
      const float4 t = part[(size_t)p * (BATCH * NPTS) + (size_t)bb * NPTS + nn + tid];
      s.x += t.x; s.y += t.y; s.z += t.z; s.w += t.w;
    }
    const float inv = 1.0f / (s.w * SC2);   // undo SC2 scaling of xyz
    srow[tid * 3 + 0] = s.x * inv;
    srow[tid * 3 + 1] = s.y * inv;
    srow[tid * 3 + 2] = s.z * inv;
  }
  __syncthreads();

  float o[4];
  const float bv = bias[lane];
#pragma unroll
  for (int r = 0; r < 4; r++) o[r] = bv;
#pragma unroll
  for (int k = 0; k < DIN; k++) {
    const float wk = W[(size_t)k * DOUT + lane];
#pragma unroll
    for (int r = 0; r < 4; r++)
      o[r] = fmaf(srow[(wv * 4 + r) * DIN + k], wk, o[r]);
  }
  __shared__ ushort lt[16][DOUT];
#pragma unroll
  for (int r = 0; r < 4; r++) {
    float m1 = o[r], m2 = o[r] * o[r];
#pragma unroll
    for (int off = 32; off > 0; off >>= 1) {
      m1 += __shfl_xor(m1, off, 64);
      m2 += __shfl_xor(m2, off, 64);
    }
    const float mu = m1 / DOUT;
    const float var = m2 / DOUT - mu * mu;
    const float rstd = rsqrtf(var + 1e-6f);
    const float v = (o[r] - mu) * rstd * g[lane] + be[lane];
    const float act = v / (1.0f + __expf(-v));
    lt[wv * 4 + r][lane] = f2bf(act);
  }
  __syncthreads();
  if (tid < DOUT) {
    ushort tmp[16];
#pragma unroll
    for (int r = 0; r < 16; r++) tmp[r] = lt[r][tid];
    ushort* dst = hout + ((size_t)bb * DOUT + tid) * NPTS + nn;
    *(uint4*)dst = *(uint4*)&tmp[0];
    *(uint4*)(dst + 8) = *(uint4*)&tmp[8];
  }
}

// ---------------------------------------------------------------------------
// gemm_v5: v5 structure with A (= w) read from precomputed Wt (2 global 16B
// loads/wave/tile — no pj LDS reads, no exp2). 64 rows/block, 512 threads
// (8 waves = row-half x j-quarter), DMA double-buffered B staging.
// ---------------------------------------------------------------------------
template <int DIN, int DOUT, bool POOL>
__global__ __launch_bounds__(512, 2) void gemm_v5(
    const ushort* __restrict__ Wt, const float4* __restrict__ part,
    const ushort* __restrict__ hT, const ushort* __restrict__ WT,
    const float* __restrict__ bias, const float* __restrict__ g,
    const float* __restrict__ be, ushort* __restrict__ hout,
    const float* __restrict__ mask, float* __restrict__ partial) {
  constexpr int NT = DIN / 16;
  constexpr int HALF = NPTS / 2;
  constexpr int TILES = HALF / 64;      // 16
  constexpr int NCOL = DOUT / 32;
  constexpr int PS = DIN + 8;
  constexpr int PN = DIN + 4;
  constexpr int SHT_B = 2 * 2 * DIN * 64 * 2;   // [buf][half][DIN][64] ushort
  constexpr int LOOP_B = SHT_B;
  constexpr int SNUM_B = 64 * PN * 4;
  constexpr int OFF_SROW = SNUM_B;
  constexpr int OFF_SINV = OFF_SROW + 64 * PS * 2;  // [64] float
  constexpr int OFF_SSTAT = OFF_SINV + 256;         // [64][2][2] float
  constexpr int EPI_B = OFF_SSTAT + 1024;
  constexpr int SMEM_B = LOOP_B > EPI_B ? LOOP_B : EPI_B;
  __shared__ __align__(16) char smem[SMEM_B];
  ushort* sht = (ushort*)smem;

  const int b = blockIdx.y;
  const int i0 = blockIdx.x * 64;
  const int tid = threadIdx.x;
  const int wv = tid >> 6, lane = tid & 63;
  const int h = (wv >> 1) & 1;   // j half
  const int u = wv & 1;          // 32-j sub-tile
  const int rg = wv >> 2;        // row half
  const int m = lane & 15, q = lane >> 4;
  const ushort* hb = hT + (size_t)b * DIN * NPTS;
  const ushort* wtb = Wt + (size_t)b * 256 * NPTS * 8;

  // A row bases: [jt][i] tiled; jt = h*128 + t*8 + u*4 + q
  const ushort* arow0 = wtb + ((size_t)(h * 128 + u * 4 + q) * NPTS + i0 + rg * 32 + m) * 8;
  const ushort* arow1 = arow0 + 16 * 8;

  f32x4 acc0[NT], acc1[NT];
#pragma unroll
  for (int nt = 0; nt < NT; nt++)
#pragma unroll
    for (int e = 0; e < 4; e++) { acc0[nt][e] = 0.f; acc1[nt][e] = 0.f; }

  constexpr int NCH = DIN / 32;            // sht DMA issues per wave
  const int srow8 = lane >> 3;
  const int scsrc = (lane & 7) ^ srow8;    // XOR-swizzled source chunk

  auto stage = [&](int t, int bf) {
    const int jb = t * 64;
#pragma unroll
    for (int i = 0; i < NCH; i++) {
      const int idx = wv * NCH + i;
      const int h2 = idx / (DIN / 8);
      const int oct = idx % (DIN / 8);
      const int row = oct * 8 + srow8;
      gl_lds16(hb + (size_t)row * NPTS + h2 * HALF + jb + scsrc * 8,
               sht + ((size_t)(bf * 2 + h2) * DIN + oct * 8) * 64);
    }
  };

  stage(0, 0);
  __syncthreads();
  for (int t = 0; t < TILES; t++) {
    const int bf = t & 1;
    if (t + 1 < TILES) stage(t + 1, bf ^ 1);   // DMA into other buffer
    const short8 af0 = *(const short8*)(arow0 + (size_t)t * 8 * NPTS * 8);
    const short8 af1 = *(const short8*)(arow1 + (size_t)t * 8 * NPTS * 8);
#pragma unroll
    for (int nt = 0; nt < NT; nt++) {
      const int d = nt * 16 + m;
      const short8 bfr = *(const short8*)
          &sht[((size_t)(bf * 2 + h) * DIN + d) * 64 + (((u * 4 + q) ^ (m & 7)) << 3)];
      acc0[nt] = __builtin_amdgcn_mfma_f32_16x16x32_bf16(af0, bfr, acc0[nt], 0, 0, 0);
      acc1[nt] = __builtin_amdgcn_mfma_f32_16x16x32_bf16(af1, bfr, acc1[nt], 0, 0, 0);
    }
    __syncthreads();
  }

  // ---- 1-slot 4-phase split-K combine in LDS (aliased over dead staging) --
  float* snum = (float*)smem;                    // [64][PN]
  ushort* srow = (ushort*)(smem + OFF_SROW);     // [64][PS]
  float* sinv = (float*)(smem + OFF_SINV);
  float* sstat = (float*)(smem + OFF_SSTAT);

  const int quarter = wv & 3;
  for (int p = 0; p < 4; p++) {
    if (quarter == p) {
      if (p == 0) {
#pragma unroll
        for (int nt = 0; nt < NT; nt++)
#pragma unroll
          for (int r = 0; r < 4; r++) {
            snum[(rg * 32 + q * 4 + r) * PN + nt * 16 + m] = acc0[nt][r];
            snum[(rg * 32 + 16 + q * 4 + r) * PN + nt * 16 + m] = acc1[nt][r];
          }
      } else {
#pragma unroll
        for (int nt = 0; nt < NT; nt++)
#pragma unroll
          for (int r = 0; r < 4; r++) {
            snum[(rg * 32 + q * 4 + r) * PN + nt * 16 + m] += acc0[nt][r];
            snum[(rg * 32 + 16 + q * 4 + r) * PN + nt * 16 + m] += acc1[nt][r];
          }
      }
    }
    __syncthreads();
  }
  if (tid < 64) {
    float d = part[(size_t)b * NPTS + i0 + tid].w;
#pragma unroll
    for (int p = 1; p < 8; p++)
      d += part[(size_t)p * (BATCH * NPTS) + (size_t)b * NPTS + i0 + tid].w;
    sinv[tid] = 1.0f / d;
  }
  __syncthreads();
  for (int idx = tid; idx < 64 * (DIN / 2); idx += 512) {
    const int r = idx / (DIN / 2), c2 = idx % (DIN / 2);
    const float v0 = snum[r * PN + 2 * c2] * sinv[r];
    const float v1 = snum[r * PN + 2 * c2 + 1] * sinv[r];
    *(unsigned int*)&srow[r * PS + 2 * c2] = pkbf(v0, v1);
  }
  __syncthreads();

  // ---- dense via MFMA: rows (wv>>1)*16.., col-half (wv&1) ----
  const int rg2 = wv >> 1, ch = wv & 1;
  short8 afrag[DIN / 32];
#pragma unroll
  for (int kt = 0; kt < DIN / 32; kt++)
    afrag[kt] = *(const short8*)&srow[(rg2 * 16 + m) * PS + kt * 32 + q * 8];
  f32x4 oacc[NCOL];
#pragma unroll
  for (int c = 0; c < NCOL; c++)
#pragma unroll
    for (int e = 0; e < 4; e++) oacc[c][e] = 0.f;
#pragma unroll
  for (int c = 0; c < NCOL; c++) {
    const int n0 = (ch * NCOL + c) * 16;
#pragma unroll
    for (int kt = 0; kt < DIN / 32; kt++) {
      const short8 bfrag = *(const short8*)(WT + (size_t)(n0 + m) * DIN + kt * 32 + q * 8);
      oacc[c] = __builtin_amdgcn_mfma_f32_16x16x32_bf16(afrag[kt], bfrag, oacc[c], 0, 0, 0);
    }
  }

  // ---- LN stats across both col-halves via LDS ----
  float bcol[NCOL];
#pragma unroll
  for (int c = 0; c < NCOL; c++) bcol[c] = bias[(ch * NCOL + c) * 16 + m];
#pragma unroll
  for (int r = 0; r < 4; r++) {
    float m1 = 0.f, m2 = 0.f;
#pragma unroll
    for (int c = 0; c < NCOL; c++) {
      const float v = oacc[c][r] + bcol[c];
      m1 += v; m2 += v * v;
    }
#pragma unroll
    for (int off = 8; off > 0; off >>= 1) {
      m1 += __shfl_xor(m1, off, 64);
      m2 += __shfl_xor(m2, off, 64);
    }
    if (m == 0) {
      const int row = rg2 * 16 + q * 4 + r;
      sstat[(row * 2 + ch) * 2 + 0] = m1;
      sstat[(row * 2 + ch) * 2 + 1] = m2;
    }
  }
  __syncthreads();

  ushort* lt = (ushort*)smem;   // [64][DOUT], aliases dead snum
  float* spl = (float*)smem;    // [4][DOUT] (POOL path)
  float pacc[NCOL];
  if (POOL) {
#pragma unroll
    for (int c = 0; c < NCOL; c++) pacc[c] = 0.f;
  }
#pragma unroll
  for (int r = 0; r < 4; r++) {
    const int row = rg2 * 16 + q * 4 + r;
    const float m1 = sstat[(row * 2 + 0) * 2 + 0] + sstat[(row * 2 + 1) * 2 + 0];
    const float m2 = sstat[(row * 2 + 0) * 2 + 1] + sstat[(row * 2 + 1) * 2 + 1];
    const float mu = m1 / DOUT;
    const float rstd = rsqrtf(m2 / DOUT - mu * mu + 1e-6f);
    float mval = 0.f;
    if (POOL) mval = mask[(size_t)b * NPTS + i0 + row];
#pragma unroll
    for (int c = 0; c < NCOL; c++) {
      const int dco = (ch * NCOL + c) * 16 + m;
      const float v = (oacc[c][r] + bcol[c] - mu) * rstd * g[dco] + be[dco];
      const float act = v / (1.0f + __expf(-v));
      if (POOL) pacc[c] = fmaf(act, mval, pacc[c]);
      else lt[row * DOUT + dco] = f2bf(act);
    }
  }
  if (POOL) {
#pragma unroll
    for (int c = 0; c < NCOL; c++) {
      float v = pacc[c];
      v += __shfl_xor(v, 16, 64);
      v += __shfl_xor(v, 32, 64);
      if (q == 0) spl[rg2 * DOUT + (ch * NCOL + c) * 16 + m] = v;
    }
    __syncthreads();
    if (tid < DOUT)
      partial[((size_t)b * (NPTS / 64) + blockIdx.x) * DOUT + tid] =
          (spl[tid] + spl[DOUT + tid]) + (spl[2 * DOUT + tid] + spl[3 * DOUT + tid]);
  } else {
    __syncthreads();
    if (tid < DOUT) {
      ushort tmp[64];
#pragma unroll
      for (int r = 0; r < 64; r++) tmp[r] = lt[r * DOUT + tid];
      ushort* dst = hout + ((size_t)b * DOUT + tid) * NPTS + i0;
#pragma unroll
      for (int c = 0; c < 8; c++)
        *(uint4*)(dst + c * 8) = *(uint4*)&tmp[c * 8];
    }
  }
}

// ---------------------------------------------------------------------------
// gemm_v6: v6 structure with A from Wt. 32 rows/block, 256 threads, 4 waves
// = {j-half}x{j-sub32}; each wave owns all 32 rows; DMA dbuf B staging.
// ---------------------------------------------------------------------------
template <int DIN, int DOUT, bool POOL, int MINW>
__global__ __launch_bounds__(256, MINW) void gemm_v6(
    const ushort* __restrict__ Wt, const float4* __restrict__ part,
    const ushort* __restrict__ hT, const ushort* __restrict__ WT,
    const float* __restrict__ bias, const float* __restrict__ g,
    const float* __restrict__ be, ushort* __restrict__ hout,
    const float* __restrict__ mask, float* __restrict__ partial) {
  constexpr int NT = DIN / 16;
  constexpr int HALF = NPTS / 2;
  constexpr int TILES = HALF / 64;
  constexpr int NCOL = DOUT / 32;
  constexpr int PS = DIN + 8;
  constexpr int PN = DIN + 4;
  constexpr int SHT_B = 2 * 2 * DIN * 64 * 2;
  constexpr int LOOP_B = SHT_B;
  constexpr int SNUM_B = 32 * PN * 4;
  constexpr int OFF_SROW = SNUM_B;
  constexpr int OFF_SINV = OFF_SROW + 32 * PS * 2;
  constexpr int OFF_SSTAT = OFF_SINV + 128;
  constexpr int EPI_B = OFF_SSTAT + 512;
  constexpr int SMEM_B = LOOP_B > EPI_B ? LOOP_B : EPI_B;
  __shared__ __align__(16) char smem[SMEM_B];
  ushort* sht = (ushort*)smem;

  const int b = blockIdx.y;
  const int i0 = blockIdx.x * 32;
  const int tid = threadIdx.x;
  const int wv = tid >> 6, lane = tid & 63;
  const int h = wv >> 1;   // j half
  const int u = wv & 1;    // 32-j sub-tile
  const int m = lane & 15, q = lane >> 4;
  const ushort* hb = hT + (size_t)b * DIN * NPTS;
  const ushort* wtb = Wt + (size_t)b * 256 * NPTS * 8;

  const ushort* arow0 = wtb + ((size_t)(h * 128 + u * 4 + q) * NPTS + i0 + m) * 8;
  const ushort* arow1 = arow0 + 16 * 8;

  f32x4 acc0[NT], acc1[NT];
#pragma unroll
  for (int nt = 0; nt < NT; nt++)
#pragma unroll
    for (int e = 0; e < 4; e++) { acc0[nt][e] = 0.f; acc1[nt][e] = 0.f; }

  constexpr int NCH = DIN / 16;
  const int srow8 = lane >> 3;
  const int scsrc = (lane & 7) ^ srow8;

  auto stage = [&](int t, int bf) {
    const int jb = t * 64;
#pragma unroll
    for (int i = 0; i < NCH; i++) {
      const int idx = wv * NCH + i;
      const int h2 = idx / (DIN / 8);
      const int oct = idx % (DIN / 8);
      const int row = oct * 8 + srow8;
      gl_lds16(hb + (size_t)row * NPTS + h2 * HALF + jb + scsrc * 8,
               sht + ((size_t)(bf * 2 + h2) * DIN + oct * 8) * 64);
    }
  };

  stage(0, 0);
  __syncthreads();
  for (int t = 0; t < TILES; t++) {
    const int bf = t & 1;
    if (t + 1 < TILES) stage(t + 1, bf ^ 1);
    const short8 af0 = *(const short8*)(arow0 + (size_t)t * 8 * NPTS * 8);
    const short8 af1 = *(const short8*)(arow1 + (size_t)t * 8 * NPTS * 8);
#pragma unroll
    for (int nt = 0; nt < NT; nt++) {
      const int d = nt * 16 + m;
      const short8 bfr = *(const short8*)
          &sht[((size_t)(bf * 2 + h) * DIN + d) * 64 + (((u * 4 + q) ^ (m & 7)) << 3)];
      acc0[nt] = __builtin_amdgcn_mfma_f32_16x16x32_bf16(af0, bfr, acc0[nt], 0, 0, 0);
      acc1[nt] = __builtin_amdgcn_mfma_f32_16x16x32_bf16(af1, bfr, acc1[nt], 0, 0, 0);
    }
    __syncthreads();
  }

  float* snum = (float*)smem;                    // [32][PN]
  ushort* srow = (ushort*)(smem + OFF_SROW);     // [32][PS]
  float* sinv = (float*)(smem + OFF_SINV);
  float* sstat = (float*)(smem + OFF_SSTAT);

  for (int p = 0; p < 4; p++) {
    if (wv == p) {
      if (p == 0) {
#pragma unroll
        for (int nt = 0; nt < NT; nt++)
#pragma unroll
          for (int r = 0; r < 4; r++) {
            snum[(q * 4 + r) * PN + nt * 16 + m] = acc0[nt][r];
            snum[(16 + q * 4 + r) * PN + nt * 16 + m] = acc1[nt][r];
          }
      } else {
#pragma unroll
        for (int nt = 0; nt < NT; nt++)
#pragma unroll
          for (int r = 0; r < 4; r++) {
            snum[(q * 4 + r) * PN + nt * 16 + m] += acc0[nt][r];
            snum[(16 + q * 4 + r) * PN + nt * 16 + m] += acc1[nt][r];
          }
      }
    }
    __syncthreads();
  }
  if (tid < 32) {
    float d = part[(size_t)b * NPTS + i0 + tid].w;
#pragma unroll
    for (int p = 1; p < 8; p++)
      d += part[(size_t)p * (BATCH * NPTS) + (size_t)b * NPTS + i0 + tid].w;
    sinv[tid] = 1.0f / d;
  }
  __syncthreads();
  for (int idx = tid; idx < 32 * (DIN / 2); idx += 256) {
    const int r = idx / (DIN / 2), c2 = idx % (DIN / 2);
    const float v0 = snum[r * PN + 2 * c2] * sinv[r];
    const float v1 = snum[r * PN + 2 * c2 + 1] * sinv[r];
    *(unsigned int*)&srow[r * PS + 2 * c2] = pkbf(v0, v1);
  }
  __syncthreads();

  const int rg2 = wv >> 1, ch = wv & 1;
  short8 afrag[DIN / 32];
#pragma unroll
  for (int kt = 0; kt < DIN / 32; kt++)
    afrag[kt] = *(const short8*)&srow[(rg2 * 16 + m) * PS + kt * 32 + q * 8];
  f32x4 oacc[NCOL];
#pragma unroll
  for (int c = 0; c < NCOL; c++)
#pragma unroll
    for (int e = 0; e < 4; e++) oacc[c][e] = 0.f;
#pragma unroll
  for (int c = 0; c < NCOL; c++) {
    const int n0 = (ch * NCOL + c) * 16;
#pragma unroll
    for (int kt = 0; kt < DIN / 32; kt++) {
      const short8 bfrag = *(const short8*)(WT + (size_t)(n0 + m) * DIN + kt * 32 + q * 8);
      oacc[c] = __builtin_amdgcn_mfma_f32_16x16x32_bf16(afrag[kt], bfrag, oacc[c], 0, 0, 0);
    }
  }

  float bcol[NCOL];
#pragma unroll
  for (int c = 0; c < NCOL; c++) bcol[c] = bias[(ch * NCOL + c) * 16 + m];
#pragma unroll
  for (int r = 0; r < 4; r++) {
    float m1 = 0.f, m2 = 0.f;
#pragma unroll
    for (int c = 0; c < NCOL; c++) {
      const float v = oacc[c][r] + bcol[c];
      m1 += v; m2 += v * v;
    }
#pragma unroll
    for (int off = 8; off > 0; off >>= 1) {
      m1 += __shfl_xor(m1, off, 64);
      m2 += __shfl_xor(m2, off, 64);
    }
    if (m == 0) {
      const int row = rg2 * 16 + q * 4 + r;
      sstat[(row * 2 + ch) * 2 + 0] = m1;
      sstat[(row * 2 + ch) * 2 + 1] = m2;
    }
  }
  __syncthreads();

  ushort* lt = (ushort*)smem;   // [32][DOUT]
  float* spl = (float*)smem;    // [2][DOUT]
  float pacc[NCOL];
  if (POOL) {
#pragma unroll
    for (int c = 0; c < NCOL; c++) pacc[c] = 0.f;
  }
#pragma unroll
  for (int r = 0; r < 4; r++) {
    const int row = rg2 * 16 + q * 4 + r;
    const float m1 = sstat[(row * 2 + 0) * 2 + 0] + sstat[(row * 2 + 1) * 2 + 0];
    const float m2 = sstat[(row * 2 + 0) * 2 + 1] + sstat[(row * 2 + 1) * 2 + 1];
    const float mu = m1 / DOUT;
    const float rstd = rsqrtf(m2 / DOUT - mu * mu + 1e-6f);
    float mval = 0.f;
    if (POOL) mval = mask[(size_t)b * NPTS + i0 + row];
#pragma unroll
    for (int c = 0; c < NCOL; c++) {
      const int dco = (ch * NCOL + c) * 16 + m;
      const float v = (oacc[c][r] + bcol[c] - mu) * rstd * g[dco] + be[dco];
      const float act = v / (1.0f + __expf(-v));
      if (POOL) pacc[c] = fmaf(act, mval, pacc[c]);
      else lt[row * DOUT + dco] = f2bf(act);
    }
  }
  if (POOL) {
#pragma unroll
    for (int c = 0; c < NCOL; c++) {
      float v = pacc[c];
      v += __shfl_xor(v, 16, 64);
      v += __shfl_xor(v, 32, 64);
      if (q == 0) spl[rg2 * DOUT + (ch * NCOL + c) * 16 + m] = v;
    }
    __syncthreads();
    if (tid < DOUT)
      partial[((size_t)b * (NPTS / 32) + blockIdx.x) * DOUT + tid] =
          spl[tid] + spl[DOUT + tid];
  } else {
    __syncthreads();
    if (tid < DOUT) {
      ushort tmp[32];
#pragma unroll
      for (int r = 0; r < 32; r++) tmp[r] = lt[r * DOUT + tid];
      ushort* dst = hout + ((size_t)b * DOUT + tid) * NPTS + i0;
#pragma unroll
      for (int c = 0; c < 4; c++)
        *(uint4*)(dst + c * 8) = *(uint4*)&tmp[c * 8];
    }
  }
}

// ---------------------------------------------------------------------------
// readout: reduce 32 partial rows/batch, /count, Dense(256->128) with
// bf16 WzT[n][k] (contiguous dwordx4 loads, dot split across 2 half-waves).
// ---------------------------------------------------------------------------
__global__ __launch_bounds__(256) void readout_kernel(
    const float* __restrict__ partial, const float* __restrict__ mask,
    const ushort* __restrict__ WzT, const float* __restrict__ bz,
    float* __restrict__ out) {
  const int b = blockIdx.x;
  const int tid = threadIdx.x;
  const float* pb = partial + (size_t)b * (NPTS / 64) * 256;
  float s0 = 0.f, s1 = 0.f, s2 = 0.f, s3 = 0.f;
#pragma unroll
  for (int p = 0; p < NPTS / 64; p += 4) {
    s0 += pb[(size_t)(p + 0) * 256 + tid];
    s1 += pb[(size_t)(p + 1) * 256 + tid];
    s2 += pb[(size_t)(p + 2) * 256 + tid];
    s3 += pb[(size_t)(p + 3) * 256 + tid];
  }
  const float s = (s0 + s1) + (s2 + s3);
  const float* mb = mask + (size_t)b * NPTS;
  float c = 0.f;
  for (int n = tid; n < NPTS; n += 256) c += mb[n];
  __shared__ float red[256];
  red[tid] = c;
  __syncthreads();
  for (int off = 128; off > 0; off >>= 1) {
    if (tid < off) red[tid] += red[tid + off];
    __syncthreads();
  }
  const float cnt = fmaxf(red[0], 1.0f);
  __shared__ float gf[256];
  gf[tid] = s / cnt;
  __syncthreads();
  const int col = tid & 127, part = tid >> 7;
  float z = 0.f;
  const ushort* wr = WzT + (size_t)col * 256 + part * 128;
  const float* gp = gf + part * 128;
#pragma unroll 4
  for (int d = 0; d < 128; d += 8) {
    const short8 w8 = *(const short8*)(wr + d);
#pragma unroll
    for (int e = 0; e < 8; e++)
      z = fmaf(gp[d + e], bf2f((ushort)w8[e]), z);
  }
  __shared__ float zred[256];
  zred[tid] = z;
  __syncthreads();
  if (tid < LATENT)
    out[(size_t)b * LATENT + tid] = bz[tid] + zred[tid] + zred[128 + tid];
}

// ---------------------------------------------------------------------------
extern "C" void kernel_launch(void* const* d_in, const int* in_sizes, int n_in,
                              void* d_out, int out_size, void* d_ws, size_t ws_size,
                              hipStream_t stream) {
  const float* x    = (const float*)d_in[0];
  const float* mask = (const float*)d_in[1];
  const float* W0   = (const float*)d_in[2];
  const float* b0   = (const float*)d_in[3];
  const float* g0   = (const float*)d_in[4];
  const float* be0  = (const float*)d_in[5];
  const float* W1   = (const float*)d_in[6];
  const float* b1   = (const float*)d_in[7];
  const float* g1   = (const float*)d_in[8];
  const float* be1  = (const float*)d_in[9];
  const float* W2   = (const float*)d_in[10];
  const float* b2   = (const float*)d_in[11];
  const float* g2   = (const float*)d_in[12];
  const float* be2  = (const float*)d_in[13];
  const float* Wz   = (const float*)d_in[14];
  const float* bz   = (const float*)d_in[15];
  float* out = (float*)d_out;

  // workspace layout (bytes, 16B-aligned regions)
  char* ws = (char*)d_ws;
  float4* pnt     = (float4*)(ws);             // 262144
  ushort* h1T     = (ushort*)(ws + 262144);    // 2097152
  ushort* h2T     = (ushort*)(ws + 2359296);   // 4194304
  float*  partial = (float*)(ws + 6553600);    // 8*32*256*4 = 262144
  ushort* WT1     = (ushort*)(ws + 6815744);   // 16384
  ushort* WT2     = (ushort*)(ws + 6832128);   // 65536
  ushort* WzT     = (ushort*)(ws + 6897664);   // 65536
  float4* part    = (float4*)(ws + 6963200);   // 8*8*2048*16 = 2097152
  ushort* Wt      = (ushort*)(ws + 9060352);   // 8*256*2048*16 = 67108864
  // total ~76 MB

  // prep + all W transposes in one launch
  setup_kernel<<<dim3(26), dim3(256), 0, stream>>>(
      x, mask, pnt, W1, WT1, W2, WT2, Wz, WzT);

  // materialize attention weights (bf16, A-layout) + layer0 agg partials
  wgen_kernel<<<dim3(8, 16, BATCH), dim3(128), 0, stream>>>(pnt, Wt, part);

  // layer 0: combine partials + dense 3->64 + LN + swish
  mlp0_kernel<<<dim3(BATCH * NPTS / 16), dim3(256), 0, stream>>>(
      part, W0, b0, g0, be0, h1T);

  // layer 1 (64 -> 128)
  gemm_v6<64, 128, false, 4><<<dim3(NPTS / 32, BATCH), dim3(256), 0, stream>>>(
      Wt, part, h1T, WT1, b1, g1, be1, h2T, nullptr, nullptr);

  // layer 2 (128 -> 256) + masked-sum pooling
  gemm_v5<128, 256, true><<<dim3(NPTS / 64, BATCH), dim3(512), 0, stream>>>(
      Wt, part, h2T, WT2, b2, g2, be2, nullptr, mask, partial);

  // readout
  readout_kernel<<<dim3(BATCH), dim3(256), 0, stream>>>(partial, mask, WzT, bz, out);
}